// Round 15
// baseline (233.043 us; speedup 1.0000x reference)
//
#include <hip/hip_runtime.h>
#include <hip/hip_fp16.h>
#include <math.h>

#define N_NODES 50000
#define N_EDGES 800000
#define D_INF   256
#define D_HID   64
#define D_OUTF  32
#define LEAKY   0.2f

#define MT 64     // gemm1 M-tile rows
#define KB 16     // gemm1 K-step

__device__ __forceinline__ float leaky_relu(float x){ return x >= 0.f ? x : LEAKY * x; }

union H4 { __half2 h[2]; float2 f; };
union H8 { __half2 h[4]; float4 f; };

typedef float f4v __attribute__((ext_vector_type(4)));

__device__ __forceinline__ float ldg_f(const float* base, unsigned byteoff){
  return *(const float*)((const char*)base + byteoff);
}
__device__ __forceinline__ int nt_ld_i(const int* p){ return __builtin_nontemporal_load(p); }
__device__ __forceinline__ void nt_st_f(float* p, float v){ __builtin_nontemporal_store(v, p); }
__device__ __forceinline__ void nt_st_i(int* p, int v){ __builtin_nontemporal_store(v, p); }
__device__ __forceinline__ void nt_st_f4(float* p, float4 v){
  f4v t = {v.x, v.y, v.z, v.w};
  __builtin_nontemporal_store(t, (f4v*)p);
}

// ---------------- CSR build ----------------
__global__ void k_deg(const int* __restrict__ dst, int* __restrict__ deg,
                      int* __restrict__ rank){
  int i = blockIdx.x * blockDim.x + threadIdx.x;
  if (i < N_EDGES){
    int d = nt_ld_i(&dst[i]);
    nt_st_i(&rank[i], atomicAdd(&deg[d], 1));
  }
}

__global__ __launch_bounds__(256) void k_scan_a(const int* __restrict__ deg, int* __restrict__ bsum){
  __shared__ int ws[4];
  int b = blockIdx.x, t = threadIdx.x, i = b * 256 + t;
  int x = (i < N_NODES) ? deg[i] : 0;
  #pragma unroll
  for (int off = 32; off; off >>= 1) x += __shfl_down(x, off, 64);
  if ((t & 63) == 0) ws[t >> 6] = x;
  __syncthreads();
  if (t == 0) bsum[b] = ws[0] + ws[1] + ws[2] + ws[3];
}

__global__ __launch_bounds__(256) void k_scan_b(int* __restrict__ bsum, int nb,
      const float* __restrict__ W2, const float* __restrict__ W3,
      const float* __restrict__ a2s, const float* __restrict__ a2d,
      const float* __restrict__ a3s, const float* __restrict__ a3d,
      float* __restrict__ prew){
  __shared__ int ws[4];
  int t = threadIdx.x, lane = t & 63, wv = t >> 6;
  int x = (t < nb) ? bsum[t] : 0;
  #pragma unroll
  for (int off = 1; off < 64; off <<= 1){
    int y = __shfl_up(x, off, 64);
    if (lane >= off) x += y;
  }
  if (lane == 63) ws[wv] = x;
  __syncthreads();
  int add = 0;
  for (int w = 0; w < wv; ++w) add += ws[w];
  x += add;
  if (t < nb) bsum[t] = x;   // inclusive

  // prew: [w2s | w2d | w3s | w3d], each 64 floats
  int vec = t >> 6, k = t & 63;
  const float* W = (vec < 2) ? W2 : W3;
  const float* a = (vec == 0) ? a2s : (vec == 1) ? a2d : (vec == 2) ? a3s : a3d;
  float s = 0.f;
  #pragma unroll 8
  for (int c = 0; c < D_OUTF; ++c) s = fmaf(W[k * D_OUTF + c], a[c], s);
  prew[t] = s;
}

__global__ __launch_bounds__(256) void k_scan_c(const int* __restrict__ deg,
        const int* __restrict__ bsum, int* __restrict__ rowptr){
  __shared__ int ws[4];
  int b = blockIdx.x, t = threadIdx.x, i = b * 256 + t;
  int lane = t & 63, wv = t >> 6;
  int x = (i < N_NODES) ? deg[i] : 0;
  #pragma unroll
  for (int off = 1; off < 64; off <<= 1){
    int y = __shfl_up(x, off, 64);
    if (lane >= off) x += y;
  }
  if (lane == 63) ws[wv] = x;
  __syncthreads();
  int add = (b > 0) ? bsum[b - 1] : 0;
  for (int w = 0; w < wv; ++w) add += ws[w];
  x += add;
  if (i < N_NODES) rowptr[i + 1] = x;
  if (b == 0 && t == 0) rowptr[0] = 0;
}

__global__ void k_fill(const int* __restrict__ src, const int* __restrict__ dst,
                       const int* __restrict__ rowptr, const int* __restrict__ rank,
                       int* __restrict__ srcs){
  int i = blockIdx.x * blockDim.x + threadIdx.x;
  if (i < N_EDGES){
    int d = nt_ld_i(&dst[i]);
    int r = nt_ld_i(&rank[i]);
    int s = nt_ld_i(&src[i]);
    nt_st_i(&srcs[rowptr[d] + r], s);
  }
}

// ---------------- layer 1 GEMM: h1 = x@W1 (tiled, fp16 out), es1/ed1 dots ----------------
__global__ __launch_bounds__(256) void k_gemm1(const float* __restrict__ x,
        const float* __restrict__ W1,
        const float* __restrict__ a_src, const float* __restrict__ a_dst,
        __half* __restrict__ h1h, float* __restrict__ es, float* __restrict__ ed){
  __shared__ float xs[2][MT][KB + 4];
  __shared__ float ws[2][KB][D_HID];
  const int tid = threadIdx.x;
  const int tc  = tid & 15;
  const int tr  = tid >> 4;
  const int row0 = blockIdx.x * MT;

  const int lxr = tid >> 2;
  const int lxp = (tid & 3) << 2;
  const int gxrow = row0 + lxr;
  const bool xok = gxrow < N_NODES;
  const float* xbase = x + (size_t)gxrow * D_INF + lxp;
  const int lwr = tid >> 4;
  const int lwp = (tid & 15) << 2;
  const float* wbase = W1 + lwr * D_HID + lwp;

  float4 xv = xok ? *(const float4*)xbase : make_float4(0.f,0.f,0.f,0.f);
  float4 wv = *(const float4*)wbase;
  *(float4*)&xs[0][lxr][lxp] = xv;
  *(float4*)&ws[0][lwr][lwp] = wv;
  __syncthreads();

  float acc[4][4] = {};
  int b = 0;
  #pragma unroll 1
  for (int ks = 0; ks < D_INF / KB; ++ks){
    if (ks < D_INF / KB - 1){
      xv = xok ? *(const float4*)(xbase + (ks + 1) * KB) : make_float4(0.f,0.f,0.f,0.f);
      wv = *(const float4*)(wbase + (size_t)(ks + 1) * KB * D_HID);
    }
    #pragma unroll
    for (int k4 = 0; k4 < KB / 4; ++k4){
      float4 xr4[4];
      #pragma unroll
      for (int r = 0; r < 4; ++r)
        xr4[r] = *(float4*)&xs[b][(tr << 2) + r][k4 << 2];
      #pragma unroll
      for (int j = 0; j < 4; ++j){
        float4 w4 = *(float4*)&ws[b][(k4 << 2) + j][tc << 2];
        #pragma unroll
        for (int r = 0; r < 4; ++r){
          float xk = (j == 0) ? xr4[r].x : (j == 1) ? xr4[r].y : (j == 2) ? xr4[r].z : xr4[r].w;
          acc[r][0] = fmaf(xk, w4.x, acc[r][0]);
          acc[r][1] = fmaf(xk, w4.y, acc[r][1]);
          acc[r][2] = fmaf(xk, w4.z, acc[r][2]);
          acc[r][3] = fmaf(xk, w4.w, acc[r][3]);
        }
      }
    }
    if (ks < D_INF / KB - 1){
      *(float4*)&xs[b ^ 1][lxr][lxp] = xv;
      *(float4*)&ws[b ^ 1][lwr][lwp] = wv;
    }
    __syncthreads();
    b ^= 1;
  }

  float as0 = a_src[tc << 2], as1 = a_src[(tc << 2) + 1],
        as2 = a_src[(tc << 2) + 2], as3 = a_src[(tc << 2) + 3];
  float ad0 = a_dst[tc << 2], ad1 = a_dst[(tc << 2) + 1],
        ad2 = a_dst[(tc << 2) + 2], ad3 = a_dst[(tc << 2) + 3];
  #pragma unroll
  for (int r = 0; r < 4; ++r){
    int row = row0 + (tr << 2) + r;
    float ps = acc[r][0]*as0 + acc[r][1]*as1 + acc[r][2]*as2 + acc[r][3]*as3;
    float pd = acc[r][0]*ad0 + acc[r][1]*ad1 + acc[r][2]*ad2 + acc[r][3]*ad3;
    #pragma unroll
    for (int off = 1; off < 16; off <<= 1){
      ps += __shfl_xor(ps, off, 64);
      pd += __shfl_xor(pd, off, 64);
    }
    if (row < N_NODES){
      H4 u;
      u.h[0] = __floats2half2_rn(acc[r][0], acc[r][1]);
      u.h[1] = __floats2half2_rn(acc[r][2], acc[r][3]);
      *(float2*)&h1h[(size_t)row * D_HID + (tc << 2)] = u.f;
      if (tc == 0){ es[row] = ps; ed[row] = pd; }
    }
  }
}

// ------- layer 1 aggregation: 16B/lane (8 rows per wave-load), bias + ELU -------
__global__ __launch_bounds__(256) void k_agg1(const int* __restrict__ rowptr,
      const int* __restrict__ srcs, const __half* __restrict__ h1,
      const float* __restrict__ es, const float* __restrict__ ed,
      const float* __restrict__ b1, __half* __restrict__ h1act){
  int t = threadIdx.x, lane = t & 63, wv = t >> 6;
  int slot = lane >> 3, cg = lane & 7;     // 8 row-slots x 8 lanes/row
  unsigned coff = cg << 4;                 // 16B within 128B row

  int node = blockIdx.x * 4 + wv;
  int beg = rowptr[node], end = rowptr[node + 1];
  float edv = ed[node];
  float4 aL = {0,0,0,0}, aH = {0,0,0,0};
  float ss = 0.f;
  for (int i = beg; i < end; i += 32){
    int sA[4]; float4 vr[4]; float p[4];
    #pragma unroll
    for (int u = 0; u < 4; ++u){
      int idx = i + (u << 3) + slot;
      sA[u] = nt_ld_i(&srcs[idx < end ? idx : end - 1]);
    }
    #pragma unroll
    for (int u = 0; u < 4; ++u)
      vr[u] = *(const float4*)((const char*)h1 + ((unsigned)sA[u] << 7) + coff);
    #pragma unroll
    for (int u = 0; u < 4; ++u){
      float e = __expf(leaky_relu(ldg_f(es, (unsigned)sA[u] << 2) + edv));
      p[u] = ((i + (u << 3) + slot) < end) ? e : 0.f;
    }
    #pragma unroll
    for (int u = 0; u < 4; ++u){
      ss += p[u];
      H8 hh; hh.f = vr[u];
      float2 c0 = __half22float2(hh.h[0]);
      float2 c1 = __half22float2(hh.h[1]);
      float2 c2 = __half22float2(hh.h[2]);
      float2 c3 = __half22float2(hh.h[3]);
      aL.x = fmaf(p[u], c0.x, aL.x); aL.y = fmaf(p[u], c0.y, aL.y);
      aL.z = fmaf(p[u], c1.x, aL.z); aL.w = fmaf(p[u], c1.y, aL.w);
      aH.x = fmaf(p[u], c2.x, aH.x); aH.y = fmaf(p[u], c2.y, aH.y);
      aH.z = fmaf(p[u], c3.x, aH.z); aH.w = fmaf(p[u], c3.y, aH.w);
    }
  }
  #pragma unroll
  for (int off = 8; off <= 32; off <<= 1){
    aL.x += __shfl_xor(aL.x, off, 64); aL.y += __shfl_xor(aL.y, off, 64);
    aL.z += __shfl_xor(aL.z, off, 64); aL.w += __shfl_xor(aL.w, off, 64);
    aH.x += __shfl_xor(aH.x, off, 64); aH.y += __shfl_xor(aH.y, off, 64);
    aH.z += __shfl_xor(aH.z, off, 64); aH.w += __shfl_xor(aH.w, off, 64);
    ss   += __shfl_xor(ss,   off, 64);
  }
  if (slot == 0){
    float inv = 1.f / (ss + 1e-16f);
    int ch0 = cg << 3;
    float4 bA = *(const float4*)&b1[ch0];
    float4 bB = *(const float4*)&b1[ch0 + 4];
    float v0 = aL.x * inv + bA.x; v0 = v0 > 0.f ? v0 : expm1f(v0);
    float v1 = aL.y * inv + bA.y; v1 = v1 > 0.f ? v1 : expm1f(v1);
    float v2 = aL.z * inv + bA.z; v2 = v2 > 0.f ? v2 : expm1f(v2);
    float v3 = aL.w * inv + bA.w; v3 = v3 > 0.f ? v3 : expm1f(v3);
    float v4 = aH.x * inv + bB.x; v4 = v4 > 0.f ? v4 : expm1f(v4);
    float v5 = aH.y * inv + bB.y; v5 = v5 > 0.f ? v5 : expm1f(v5);
    float v6 = aH.z * inv + bB.z; v6 = v6 > 0.f ? v6 : expm1f(v6);
    float v7 = aH.w * inv + bB.w; v7 = v7 > 0.f ? v7 : expm1f(v7);
    H8 o;
    o.h[0] = __floats2half2_rn(v0, v1);
    o.h[1] = __floats2half2_rn(v2, v3);
    o.h[2] = __floats2half2_rn(v4, v5);
    o.h[3] = __floats2half2_rn(v6, v7);
    nt_st_f4((float*)&h1act[(size_t)node * D_HID + ch0], o.f);
  }
}

// ---- dense GEMM: h23 = h1act @ [W2|W3] -> fp16, + fused attention dots ----
__global__ __launch_bounds__(256) void k_gemm23(const __half* __restrict__ h1acth,
        const float* __restrict__ W2, const float* __restrict__ W3,
        const float* __restrict__ prew,
        __half* __restrict__ h23h, float2* __restrict__ es23,
        float2* __restrict__ edinv2, float* __restrict__ ed3){
  __shared__ float hs[64][68];
  __shared__ float wsd[64][64];
  __shared__ float sprew[256];
  const int tid = threadIdx.x;
  const int row0 = blockIdx.x * 64;

  {
    int r = tid >> 2, cg = tid & 3;
    int grow = row0 + r;
    bool ok = grow < N_NODES;
    const float4* hrow = (const float4*)(h1acth + (size_t)grow * D_HID + cg * 16);
    H8 q0, q1;
    q0.f = ok ? hrow[0] : make_float4(0,0,0,0);
    q1.f = ok ? hrow[1] : make_float4(0,0,0,0);
    float* dsth = &hs[r][cg * 16];
    #pragma unroll
    for (int j = 0; j < 4; ++j){
      float2 f = __half22float2(q0.h[j]);
      dsth[j * 2] = f.x; dsth[j * 2 + 1] = f.y;
    }
    #pragma unroll
    for (int j = 0; j < 4; ++j){
      float2 f = __half22float2(q1.h[j]);
      dsth[8 + j * 2] = f.x; dsth[8 + j * 2 + 1] = f.y;
    }
    int k = tid >> 2;
    const float* Wsrc = (cg < 2) ? W2 : W3;
    int cbase = (cg & 1) * 16;
    float4* dstw = (float4*)&wsd[k][cg * 16];
    const float4* srcw = (const float4*)&Wsrc[k * D_OUTF + cbase];
    #pragma unroll
    for (int j = 0; j < 4; ++j) dstw[j] = srcw[j];
    sprew[tid] = prew[tid];
  }
  __syncthreads();

  // fused attention-dot scalars: row r by 4 lanes (16-ch quarters)
  {
    int r = tid >> 2, q = tid & 3, row = row0 + r;
    float d0 = 0.f, d1 = 0.f, d2 = 0.f, d3 = 0.f;
    #pragma unroll
    for (int k = 0; k < 16; ++k){
      float hval = hs[r][(q << 4) + k];
      d0 = fmaf(hval, sprew[(q << 4) + k], d0);
      d1 = fmaf(hval, sprew[64 + (q << 4) + k], d1);
      d2 = fmaf(hval, sprew[128 + (q << 4) + k], d2);
      d3 = fmaf(hval, sprew[192 + (q << 4) + k], d3);
    }
    #pragma unroll
    for (int off = 1; off < 4; off <<= 1){
      d0 += __shfl_xor(d0, off, 64);
      d1 += __shfl_xor(d1, off, 64);
      d2 += __shfl_xor(d2, off, 64);
      d3 += __shfl_xor(d3, off, 64);
    }
    if (q == 0 && row < N_NODES){
      es23[row] = make_float2(d0, d2);
      edinv2[row].x = d1;
      ed3[row] = d3;
    }
  }

  const int tc = tid & 15, tr = tid >> 4;
  float acc[4][4] = {};
  #pragma unroll
  for (int k4 = 0; k4 < 16; ++k4){
    float4 xr4[4];
    #pragma unroll
    for (int r = 0; r < 4; ++r)
      xr4[r] = *(float4*)&hs[(tr << 2) + r][k4 << 2];
    #pragma unroll
    for (int j = 0; j < 4; ++j){
      float4 w4 = *(float4*)&wsd[(k4 << 2) + j][tc << 2];
      #pragma unroll
      for (int r = 0; r < 4; ++r){
        float xk = (j == 0) ? xr4[r].x : (j == 1) ? xr4[r].y : (j == 2) ? xr4[r].z : xr4[r].w;
        acc[r][0] = fmaf(xk, w4.x, acc[r][0]);
        acc[r][1] = fmaf(xk, w4.y, acc[r][1]);
        acc[r][2] = fmaf(xk, w4.z, acc[r][2]);
        acc[r][3] = fmaf(xk, w4.w, acc[r][3]);
      }
    }
  }
  #pragma unroll
  for (int r = 0; r < 4; ++r){
    int row = row0 + (tr << 2) + r;
    if (row < N_NODES){
      H4 u;
      u.h[0] = __floats2half2_rn(acc[r][0], acc[r][1]);
      u.h[1] = __floats2half2_rn(acc[r][2], acc[r][3]);
      *(float2*)&h23h[(size_t)row * 64 + (tc << 2)] = u.f;
    }
  }
}

// ------- layers 2&3 aggregation: 16B/lane, relu + linear + var (no alpha scatter) -------
__global__ __launch_bounds__(256) void k_agg23(const int* __restrict__ rowptr,
   const int* __restrict__ srcs, const __half* __restrict__ h23,
   const float2* __restrict__ es23, float2* __restrict__ edinv2,
   const float* __restrict__ ed3,
   const float* __restrict__ b2, const float* __restrict__ b3,
   const float* __restrict__ Wlin, const float* __restrict__ blin,
   float* __restrict__ mean_out, float* __restrict__ var_out){
  __shared__ float sWl[D_OUTF * D_OUTF];
  int t = threadIdx.x, lane = t & 63, wv = t >> 6;
  int slot = lane >> 3, cg = lane & 7;
  int layer = cg >> 2;                 // cg 0-3: layer2 (ch 0-31), cg 4-7: layer3 (ch 32-63)
  unsigned coff = cg << 4;
  for (int idx = t; idx < D_OUTF * D_OUTF; idx += 256) sWl[idx] = Wlin[idx];
  __syncthreads();

  int node = blockIdx.x * 4 + wv;
  int beg = rowptr[node], end = rowptr[node + 1];
  float edv = layer ? ed3[node] : edinv2[node].x;
  float4 aL = {0,0,0,0}, aH = {0,0,0,0};
  float ss = 0.f;
  for (int i = beg; i < end; i += 32){
    int sA[4]; float4 vr[4]; float p[4];
    #pragma unroll
    for (int u = 0; u < 4; ++u){
      int idx = i + (u << 3) + slot;
      sA[u] = nt_ld_i(&srcs[idx < end ? idx : end - 1]);
    }
    #pragma unroll
    for (int u = 0; u < 4; ++u)
      vr[u] = *(const float4*)((const char*)h23 + ((unsigned)sA[u] << 7) + coff);
    #pragma unroll
    for (int u = 0; u < 4; ++u){
      float2 e2 = *(const float2*)((const char*)es23 + ((unsigned)sA[u] << 3));
      float esv = layer ? e2.y : e2.x;
      float e = __expf(leaky_relu(esv + edv));
      p[u] = ((i + (u << 3) + slot) < end) ? e : 0.f;
    }
    #pragma unroll
    for (int u = 0; u < 4; ++u){
      ss += p[u];
      H8 hh; hh.f = vr[u];
      float2 c0 = __half22float2(hh.h[0]);
      float2 c1 = __half22float2(hh.h[1]);
      float2 c2 = __half22float2(hh.h[2]);
      float2 c3 = __half22float2(hh.h[3]);
      aL.x = fmaf(p[u], c0.x, aL.x); aL.y = fmaf(p[u], c0.y, aL.y);
      aL.z = fmaf(p[u], c1.x, aL.z); aL.w = fmaf(p[u], c1.y, aL.w);
      aH.x = fmaf(p[u], c2.x, aH.x); aH.y = fmaf(p[u], c2.y, aH.y);
      aH.z = fmaf(p[u], c3.x, aH.z); aH.w = fmaf(p[u], c3.y, aH.w);
    }
  }
  #pragma unroll
  for (int off = 8; off <= 32; off <<= 1){
    aL.x += __shfl_xor(aL.x, off, 64); aL.y += __shfl_xor(aL.y, off, 64);
    aL.z += __shfl_xor(aL.z, off, 64); aL.w += __shfl_xor(aL.w, off, 64);
    aH.x += __shfl_xor(aH.x, off, 64); aH.y += __shfl_xor(aH.y, off, 64);
    aH.z += __shfl_xor(aH.z, off, 64); aH.w += __shfl_xor(aH.w, off, 64);
    ss   += __shfl_xor(ss,   off, 64);
  }

  // layer-3 self loop (gated to layer lanes; wave-uniform scalars)
  {
    float psr = __expf(leaky_relu(es23[node].y + ed3[node]));
    float psg = layer ? psr : 0.f;
    H8 hh; hh.f = *(const float4*)((const char*)h23 + ((unsigned)node << 7) + coff);
    float2 c0 = __half22float2(hh.h[0]);
    float2 c1 = __half22float2(hh.h[1]);
    float2 c2 = __half22float2(hh.h[2]);
    float2 c3 = __half22float2(hh.h[3]);
    aL.x = fmaf(psg, c0.x, aL.x); aL.y = fmaf(psg, c0.y, aL.y);
    aL.z = fmaf(psg, c1.x, aL.z); aL.w = fmaf(psg, c1.y, aL.w);
    aH.x = fmaf(psg, c2.x, aH.x); aH.y = fmaf(psg, c2.y, aH.y);
    aH.z = fmaf(psg, c3.x, aH.z); aH.w = fmaf(psg, c3.y, aH.w);
    ss += psg;
  }
  float inv = 1.f / (ss + 1e-16f);

  float m0=0,m1=0,m2=0,m3=0,m4=0,m5=0,m6=0,m7=0;
  if (!layer){
    int ch0 = cg << 3;
    float4 bA = *(const float4*)&b2[ch0];
    float4 bB = *(const float4*)&b2[ch0 + 4];
    m0 = aL.x * inv + bA.x; m0 = m0 > 0.f ? m0 : 0.f;
    m1 = aL.y * inv + bA.y; m1 = m1 > 0.f ? m1 : 0.f;
    m2 = aL.z * inv + bA.z; m2 = m2 > 0.f ? m2 : 0.f;
    m3 = aL.w * inv + bA.w; m3 = m3 > 0.f ? m3 : 0.f;
    m4 = aH.x * inv + bB.x; m4 = m4 > 0.f ? m4 : 0.f;
    m5 = aH.y * inv + bB.y; m5 = m5 > 0.f ? m5 : 0.f;
    m6 = aH.z * inv + bB.z; m6 = m6 > 0.f ? m6 : 0.f;
    m7 = aH.w * inv + bB.w; m7 = m7 > 0.f ? m7 : 0.f;
  } else if (slot == 0){
    int ch0 = (cg & 3) << 3;
    float4 bA = *(const float4*)&b3[ch0];
    float4 bB = *(const float4*)&b3[ch0 + 4];
    float4 oA = { aL.x * inv + bA.x, aL.y * inv + bA.y, aL.z * inv + bA.z, aL.w * inv + bA.w };
    float4 oB = { aH.x * inv + bB.x, aH.y * inv + bB.y, aH.z * inv + bB.z, aH.w * inv + bB.w };
    nt_st_f4(&var_out[(size_t)node * D_OUTF + ch0],     oA);
    nt_st_f4(&var_out[(size_t)node * D_OUTF + ch0 + 4], oB);
  }

  // final linear on mean: out channel c = lane&31; mean regs live on lanes 0-3
  {
    int c = lane & 31;
    float o = blin[c];
    #pragma unroll
    for (int cgs = 0; cgs < 4; ++cgs){
      float q0 = __shfl(m0, cgs, 64), q1 = __shfl(m1, cgs, 64);
      float q2 = __shfl(m2, cgs, 64), q3 = __shfl(m3, cgs, 64);
      float q4 = __shfl(m4, cgs, 64), q5 = __shfl(m5, cgs, 64);
      float q6 = __shfl(m6, cgs, 64), q7 = __shfl(m7, cgs, 64);
      int j0 = cgs << 3;
      o = fmaf(q0, sWl[(j0+0) * D_OUTF + c], o);
      o = fmaf(q1, sWl[(j0+1) * D_OUTF + c], o);
      o = fmaf(q2, sWl[(j0+2) * D_OUTF + c], o);
      o = fmaf(q3, sWl[(j0+3) * D_OUTF + c], o);
      o = fmaf(q4, sWl[(j0+4) * D_OUTF + c], o);
      o = fmaf(q5, sWl[(j0+5) * D_OUTF + c], o);
      o = fmaf(q6, sWl[(j0+6) * D_OUTF + c], o);
      o = fmaf(q7, sWl[(j0+7) * D_OUTF + c], o);
    }
    if (lane < 32) nt_st_f(&mean_out[(size_t)node * D_OUTF + c], o);
  }
  if (lane == 0) edinv2[node].y = inv;   // lane 0 is layer-2
}

// ------- alpha: flat edge-parallel, coalesced write, L2-hot gathers -------
__global__ __launch_bounds__(256) void k_alpha(const int* __restrict__ src,
    const int* __restrict__ dst,
    const float2* __restrict__ es23, const float2* __restrict__ edinv2,
    float* __restrict__ alpha_out){
  int e = blockIdx.x * blockDim.x + threadIdx.x;
  if (e < N_EDGES){
    int s = nt_ld_i(&src[e]), d = nt_ld_i(&dst[e]);
    float2 ei = *(const float2*)((const char*)edinv2 + ((unsigned)d << 3));
    float esv = ((const float2*)((const char*)es23 + ((unsigned)s << 3)))->x;
    nt_st_f(&alpha_out[e], __expf(leaky_relu(esv + ei.x)) * ei.y);
  }
}

extern "C" void kernel_launch(void* const* d_in, const int* in_sizes, int n_in,
                              void* d_out, int out_size, void* d_ws, size_t ws_size,
                              hipStream_t stream) {
  const float* x   = (const float*)d_in[0];
  const int*   ei  = (const int*)d_in[1];
  const int*   src = ei;
  const int*   dst = ei + N_EDGES;
  const float* W1  = (const float*)d_in[2];
  const float* a1s = (const float*)d_in[3];
  const float* a1d = (const float*)d_in[4];
  const float* b1  = (const float*)d_in[5];
  const float* W2  = (const float*)d_in[6];
  const float* a2s = (const float*)d_in[7];
  const float* a2d = (const float*)d_in[8];
  const float* b2  = (const float*)d_in[9];
  const float* W3  = (const float*)d_in[10];
  const float* a3s = (const float*)d_in[11];
  const float* a3d = (const float*)d_in[12];
  const float* b3  = (const float*)d_in[13];
  const float* Wl  = (const float*)d_in[14];
  const float* bl  = (const float*)d_in[15];

  float* out       = (float*)d_out;
  float* mean_out  = out;
  float* var_out   = out + (size_t)N_NODES * D_OUTF;
  float* alpha_out = out + 2 * (size_t)N_NODES * D_OUTF;

  const int NSCAN = (N_NODES + 255) / 256;       // 196

  int* deg      = (int*)d_ws;                 // N
  int* rowptr   = deg + N_NODES;              // N+1
  int* bsum     = rowptr + (N_NODES + 1);     // NSCAN
  int* rank     = bsum + NSCAN;               // E
  int* srcs     = rank + N_EDGES;             // E
  size_t ioff   = (size_t)((srcs + N_EDGES) - (int*)d_ws);
  ioff = (ioff + 3) & ~(size_t)3;             // 16B align for half tables
  __half* h1    = (__half*)((int*)d_ws + ioff);     // N*64
  __half* h1act = h1 + (size_t)N_NODES * 64;        // N*64
  __half* h23   = h1act + (size_t)N_NODES * 64;     // N*64
  float* es1    = (float*)(h23 + (size_t)N_NODES * 64);
  float* ed1    = es1 + N_NODES;
  float* ed3    = ed1 + N_NODES;
  float* prew   = ed3 + N_NODES;              // 256 floats
  float2* es23  = (float2*)(prew + 256);
  float2* edinv2= es23 + N_NODES;

  hipMemsetAsync(deg, 0, (size_t)N_NODES * sizeof(int), stream);

  k_deg   <<<(N_EDGES + 255) / 256, 256, 0, stream>>>(dst, deg, rank);
  k_scan_a<<<NSCAN, 256, 0, stream>>>(deg, bsum);
  k_scan_b<<<1, 256, 0, stream>>>(bsum, NSCAN, W2, W3, a2s, a2d, a3s, a3d, prew);
  k_scan_c<<<NSCAN, 256, 0, stream>>>(deg, bsum, rowptr);
  k_fill  <<<(N_EDGES + 255) / 256, 256, 0, stream>>>(src, dst, rowptr, rank, srcs);

  k_gemm1<<<(N_NODES + MT - 1) / MT, 256, 0, stream>>>(x, W1, a1s, a1d, h1, es1, ed1);
  k_agg1 <<<N_NODES / 4, 256, 0, stream>>>(rowptr, srcs, h1, es1, ed1, b1, h1act);
  k_gemm23<<<(N_NODES + 63) / 64, 256, 0, stream>>>(h1act, W2, W3, prew,
                                                    h23, es23, edinv2, ed3);
  k_agg23<<<N_NODES / 4, 256, 0, stream>>>(rowptr, srcs, h23, es23, edinv2, ed3,
                                           b2, b3, Wl, bl, mean_out, var_out);
  k_alpha<<<(N_EDGES + 255) / 256, 256, 0, stream>>>(src, dst, es23, edinv2, alpha_out);
}

// Round 16
// 190.377 us; speedup vs baseline: 1.2241x; 1.2241x over previous
//
#include <hip/hip_runtime.h>
#include <hip/hip_fp16.h>
#include <math.h>

#define N_NODES 50000
#define N_EDGES 800000
#define D_INF   256
#define D_HID   64
#define D_OUTF  32
#define LEAKY   0.2f

#define MT 64     // gemm1 M-tile rows
#define KB 16     // gemm1 K-step

__device__ __forceinline__ float leaky_relu(float x){ return x >= 0.f ? x : LEAKY * x; }

union H4 { __half2 h[2]; float2 f; };
union H8 { __half2 h[4]; float4 f; };

__device__ __forceinline__ float ldg_f(const float* base, unsigned byteoff){
  return *(const float*)((const char*)base + byteoff);
}

// ---------------- CSR build ----------------
__global__ void k_deg(const int* __restrict__ dst, int* __restrict__ deg,
                      int* __restrict__ rank){
  int i = blockIdx.x * blockDim.x + threadIdx.x;
  if (i < N_EDGES) rank[i] = atomicAdd(&deg[dst[i]], 1);
}

__global__ __launch_bounds__(256) void k_scan_a(const int* __restrict__ deg, int* __restrict__ bsum){
  __shared__ int ws[4];
  int b = blockIdx.x, t = threadIdx.x, i = b * 256 + t;
  int x = (i < N_NODES) ? deg[i] : 0;
  #pragma unroll
  for (int off = 32; off; off >>= 1) x += __shfl_down(x, off, 64);
  if ((t & 63) == 0) ws[t >> 6] = x;
  __syncthreads();
  if (t == 0) bsum[b] = ws[0] + ws[1] + ws[2] + ws[3];
}

__global__ __launch_bounds__(256) void k_scan_b(int* __restrict__ bsum, int nb,
      const float* __restrict__ W2, const float* __restrict__ W3,
      const float* __restrict__ a2s, const float* __restrict__ a2d,
      const float* __restrict__ a3s, const float* __restrict__ a3d,
      float* __restrict__ prew){
  __shared__ int ws[4];
  int t = threadIdx.x, lane = t & 63, wv = t >> 6;
  int x = (t < nb) ? bsum[t] : 0;
  #pragma unroll
  for (int off = 1; off < 64; off <<= 1){
    int y = __shfl_up(x, off, 64);
    if (lane >= off) x += y;
  }
  if (lane == 63) ws[wv] = x;
  __syncthreads();
  int add = 0;
  for (int w = 0; w < wv; ++w) add += ws[w];
  x += add;
  if (t < nb) bsum[t] = x;   // inclusive

  // prew: [w2s | w2d | w3s | w3d], each 64 floats
  int vec = t >> 6, k = t & 63;
  const float* W = (vec < 2) ? W2 : W3;
  const float* a = (vec == 0) ? a2s : (vec == 1) ? a2d : (vec == 2) ? a3s : a3d;
  float s = 0.f;
  #pragma unroll 8
  for (int c = 0; c < D_OUTF; ++c) s = fmaf(W[k * D_OUTF + c], a[c], s);
  prew[t] = s;
}

__global__ __launch_bounds__(256) void k_scan_c(const int* __restrict__ deg,
        const int* __restrict__ bsum, int* __restrict__ rowptr){
  __shared__ int ws[4];
  int b = blockIdx.x, t = threadIdx.x, i = b * 256 + t;
  int lane = t & 63, wv = t >> 6;
  int x = (i < N_NODES) ? deg[i] : 0;
  #pragma unroll
  for (int off = 1; off < 64; off <<= 1){
    int y = __shfl_up(x, off, 64);
    if (lane >= off) x += y;
  }
  if (lane == 63) ws[wv] = x;
  __syncthreads();
  int add = (b > 0) ? bsum[b - 1] : 0;
  for (int w = 0; w < wv; ++w) add += ws[w];
  x += add;
  if (i < N_NODES) rowptr[i + 1] = x;
  if (b == 0 && t == 0) rowptr[0] = 0;
}

__global__ void k_fill(const int* __restrict__ src, const int* __restrict__ dst,
                       const int* __restrict__ rowptr, const int* __restrict__ rank,
                       int* __restrict__ srcs){
  int i = blockIdx.x * blockDim.x + threadIdx.x;
  if (i < N_EDGES){
    srcs[rowptr[dst[i]] + rank[i]] = src[i];
  }
}

// ---------------- layer 1 GEMM: h1 = x@W1 (tiled, fp16 out), es1/ed1 dots ----------------
__global__ __launch_bounds__(256) void k_gemm1(const float* __restrict__ x,
        const float* __restrict__ W1,
        const float* __restrict__ a_src, const float* __restrict__ a_dst,
        __half* __restrict__ h1h, float* __restrict__ es, float* __restrict__ ed){
  __shared__ float xs[2][MT][KB + 4];
  __shared__ float ws[2][KB][D_HID];
  const int tid = threadIdx.x;
  const int tc  = tid & 15;
  const int tr  = tid >> 4;
  const int row0 = blockIdx.x * MT;

  const int lxr = tid >> 2;
  const int lxp = (tid & 3) << 2;
  const int gxrow = row0 + lxr;
  const bool xok = gxrow < N_NODES;
  const float* xbase = x + (size_t)gxrow * D_INF + lxp;
  const int lwr = tid >> 4;
  const int lwp = (tid & 15) << 2;
  const float* wbase = W1 + lwr * D_HID + lwp;

  float4 xv = xok ? *(const float4*)xbase : make_float4(0.f,0.f,0.f,0.f);
  float4 wv = *(const float4*)wbase;
  *(float4*)&xs[0][lxr][lxp] = xv;
  *(float4*)&ws[0][lwr][lwp] = wv;
  __syncthreads();

  float acc[4][4] = {};
  int b = 0;
  #pragma unroll 1
  for (int ks = 0; ks < D_INF / KB; ++ks){
    if (ks < D_INF / KB - 1){
      xv = xok ? *(const float4*)(xbase + (ks + 1) * KB) : make_float4(0.f,0.f,0.f,0.f);
      wv = *(const float4*)(wbase + (size_t)(ks + 1) * KB * D_HID);
    }
    #pragma unroll
    for (int k4 = 0; k4 < KB / 4; ++k4){
      float4 xr4[4];
      #pragma unroll
      for (int r = 0; r < 4; ++r)
        xr4[r] = *(float4*)&xs[b][(tr << 2) + r][k4 << 2];
      #pragma unroll
      for (int j = 0; j < 4; ++j){
        float4 w4 = *(float4*)&ws[b][(k4 << 2) + j][tc << 2];
        #pragma unroll
        for (int r = 0; r < 4; ++r){
          float xk = (j == 0) ? xr4[r].x : (j == 1) ? xr4[r].y : (j == 2) ? xr4[r].z : xr4[r].w;
          acc[r][0] = fmaf(xk, w4.x, acc[r][0]);
          acc[r][1] = fmaf(xk, w4.y, acc[r][1]);
          acc[r][2] = fmaf(xk, w4.z, acc[r][2]);
          acc[r][3] = fmaf(xk, w4.w, acc[r][3]);
        }
      }
    }
    if (ks < D_INF / KB - 1){
      *(float4*)&xs[b ^ 1][lxr][lxp] = xv;
      *(float4*)&ws[b ^ 1][lwr][lwp] = wv;
    }
    __syncthreads();
    b ^= 1;
  }

  float as0 = a_src[tc << 2], as1 = a_src[(tc << 2) + 1],
        as2 = a_src[(tc << 2) + 2], as3 = a_src[(tc << 2) + 3];
  float ad0 = a_dst[tc << 2], ad1 = a_dst[(tc << 2) + 1],
        ad2 = a_dst[(tc << 2) + 2], ad3 = a_dst[(tc << 2) + 3];
  #pragma unroll
  for (int r = 0; r < 4; ++r){
    int row = row0 + (tr << 2) + r;
    float ps = acc[r][0]*as0 + acc[r][1]*as1 + acc[r][2]*as2 + acc[r][3]*as3;
    float pd = acc[r][0]*ad0 + acc[r][1]*ad1 + acc[r][2]*ad2 + acc[r][3]*ad3;
    #pragma unroll
    for (int off = 1; off < 16; off <<= 1){
      ps += __shfl_xor(ps, off, 64);
      pd += __shfl_xor(pd, off, 64);
    }
    if (row < N_NODES){
      H4 u;
      u.h[0] = __floats2half2_rn(acc[r][0], acc[r][1]);
      u.h[1] = __floats2half2_rn(acc[r][2], acc[r][3]);
      *(float2*)&h1h[(size_t)row * D_HID + (tc << 2)] = u.f;
      if (tc == 0){ es[row] = ps; ed[row] = pd; }
    }
  }
}

// ------- layer 1 aggregation: 2 nodes/wave, 16B/lane, stride 16/node, bias + ELU -------
__global__ __launch_bounds__(256) void k_agg1(const int* __restrict__ rowptr,
      const int* __restrict__ srcs, const __half* __restrict__ h1,
      const float* __restrict__ es, const float* __restrict__ ed,
      const float* __restrict__ b1, __half* __restrict__ h1act){
  int t = threadIdx.x, lane = t & 63, wv = t >> 6;
  int nh = lane >> 5, sub = lane & 31;
  int slot2 = sub >> 3, cg = sub & 7;      // 4 row-slots x 8 lanes/row per half-wave
  unsigned coff = cg << 4;                 // 16B within 128B row

  int node = blockIdx.x * 8 + wv * 2 + nh;
  int beg = rowptr[node], end = rowptr[node + 1];
  int len = end - beg;
  int lenO = __shfl_xor(len, 32, 64);
  int lenmax = len > lenO ? len : lenO;
  int fallback = (len > 0) ? end - 1 : 0;
  float edv = ed[node];
  float4 aL = {0,0,0,0}, aH = {0,0,0,0};
  float ss = 0.f;
  for (int off = 0; off < lenmax; off += 16){
    int sA[4]; float4 vr[4]; float p[4];
    #pragma unroll
    for (int u = 0; u < 4; ++u){
      int idx = beg + off + (u << 2) + slot2;
      sA[u] = srcs[idx < end ? idx : fallback];
    }
    #pragma unroll
    for (int u = 0; u < 4; ++u)
      vr[u] = *(const float4*)((const char*)h1 + ((unsigned)sA[u] << 7) + coff);
    #pragma unroll
    for (int u = 0; u < 4; ++u){
      float e = __expf(leaky_relu(ldg_f(es, (unsigned)sA[u] << 2) + edv));
      p[u] = ((off + (u << 2) + slot2) < len) ? e : 0.f;
    }
    #pragma unroll
    for (int u = 0; u < 4; ++u){
      ss += p[u];
      H8 hh; hh.f = vr[u];
      float2 c0 = __half22float2(hh.h[0]);
      float2 c1 = __half22float2(hh.h[1]);
      float2 c2 = __half22float2(hh.h[2]);
      float2 c3 = __half22float2(hh.h[3]);
      aL.x = fmaf(p[u], c0.x, aL.x); aL.y = fmaf(p[u], c0.y, aL.y);
      aL.z = fmaf(p[u], c1.x, aL.z); aL.w = fmaf(p[u], c1.y, aL.w);
      aH.x = fmaf(p[u], c2.x, aH.x); aH.y = fmaf(p[u], c2.y, aH.y);
      aH.z = fmaf(p[u], c3.x, aH.z); aH.w = fmaf(p[u], c3.y, aH.w);
    }
  }
  // reduce across the 4 slots of each half-wave (lane bits 3,4 only)
  #pragma unroll
  for (int off = 8; off <= 16; off <<= 1){
    aL.x += __shfl_xor(aL.x, off, 64); aL.y += __shfl_xor(aL.y, off, 64);
    aL.z += __shfl_xor(aL.z, off, 64); aL.w += __shfl_xor(aL.w, off, 64);
    aH.x += __shfl_xor(aH.x, off, 64); aH.y += __shfl_xor(aH.y, off, 64);
    aH.z += __shfl_xor(aH.z, off, 64); aH.w += __shfl_xor(aH.w, off, 64);
    ss   += __shfl_xor(ss,   off, 64);
  }
  if (slot2 == 0){
    float inv = 1.f / (ss + 1e-16f);
    int ch0 = cg << 3;
    float4 bA = *(const float4*)&b1[ch0];
    float4 bB = *(const float4*)&b1[ch0 + 4];
    float v0 = aL.x * inv + bA.x; v0 = v0 > 0.f ? v0 : expm1f(v0);
    float v1 = aL.y * inv + bA.y; v1 = v1 > 0.f ? v1 : expm1f(v1);
    float v2 = aL.z * inv + bA.z; v2 = v2 > 0.f ? v2 : expm1f(v2);
    float v3 = aL.w * inv + bA.w; v3 = v3 > 0.f ? v3 : expm1f(v3);
    float v4 = aH.x * inv + bB.x; v4 = v4 > 0.f ? v4 : expm1f(v4);
    float v5 = aH.y * inv + bB.y; v5 = v5 > 0.f ? v5 : expm1f(v5);
    float v6 = aH.z * inv + bB.z; v6 = v6 > 0.f ? v6 : expm1f(v6);
    float v7 = aH.w * inv + bB.w; v7 = v7 > 0.f ? v7 : expm1f(v7);
    H8 o;
    o.h[0] = __floats2half2_rn(v0, v1);
    o.h[1] = __floats2half2_rn(v2, v3);
    o.h[2] = __floats2half2_rn(v4, v5);
    o.h[3] = __floats2half2_rn(v6, v7);
    *(float4*)&h1act[(size_t)node * D_HID + ch0] = o.f;
  }
}

// ---- dense GEMM: h23 = h1act @ [W2|W3] -> fp16, + fused attention dots ----
__global__ __launch_bounds__(256) void k_gemm23(const __half* __restrict__ h1acth,
        const float* __restrict__ W2, const float* __restrict__ W3,
        const float* __restrict__ prew,
        __half* __restrict__ h23h, float2* __restrict__ es23,
        float2* __restrict__ edinv2, float* __restrict__ ed3){
  __shared__ float hs[64][68];
  __shared__ float wsd[64][64];
  __shared__ float sprew[256];
  const int tid = threadIdx.x;
  const int row0 = blockIdx.x * 64;

  {
    int r = tid >> 2, cg = tid & 3;
    int grow = row0 + r;
    bool ok = grow < N_NODES;
    const float4* hrow = (const float4*)(h1acth + (size_t)grow * D_HID + cg * 16);
    H8 q0, q1;
    q0.f = ok ? hrow[0] : make_float4(0,0,0,0);
    q1.f = ok ? hrow[1] : make_float4(0,0,0,0);
    float* dsth = &hs[r][cg * 16];
    #pragma unroll
    for (int j = 0; j < 4; ++j){
      float2 f = __half22float2(q0.h[j]);
      dsth[j * 2] = f.x; dsth[j * 2 + 1] = f.y;
    }
    #pragma unroll
    for (int j = 0; j < 4; ++j){
      float2 f = __half22float2(q1.h[j]);
      dsth[8 + j * 2] = f.x; dsth[8 + j * 2 + 1] = f.y;
    }
    int k = tid >> 2;
    const float* Wsrc = (cg < 2) ? W2 : W3;
    int cbase = (cg & 1) * 16;
    float4* dstw = (float4*)&wsd[k][cg * 16];
    const float4* srcw = (const float4*)&Wsrc[k * D_OUTF + cbase];
    #pragma unroll
    for (int j = 0; j < 4; ++j) dstw[j] = srcw[j];
    sprew[tid] = prew[tid];
  }
  __syncthreads();

  // fused attention-dot scalars: row r by 4 lanes (16-ch quarters)
  {
    int r = tid >> 2, q = tid & 3, row = row0 + r;
    float d0 = 0.f, d1 = 0.f, d2 = 0.f, d3 = 0.f;
    #pragma unroll
    for (int k = 0; k < 16; ++k){
      float hval = hs[r][(q << 4) + k];
      d0 = fmaf(hval, sprew[(q << 4) + k], d0);
      d1 = fmaf(hval, sprew[64 + (q << 4) + k], d1);
      d2 = fmaf(hval, sprew[128 + (q << 4) + k], d2);
      d3 = fmaf(hval, sprew[192 + (q << 4) + k], d3);
    }
    #pragma unroll
    for (int off = 1; off < 4; off <<= 1){
      d0 += __shfl_xor(d0, off, 64);
      d1 += __shfl_xor(d1, off, 64);
      d2 += __shfl_xor(d2, off, 64);
      d3 += __shfl_xor(d3, off, 64);
    }
    if (q == 0 && row < N_NODES){
      es23[row] = make_float2(d0, d2);
      edinv2[row].x = d1;
      ed3[row] = d3;
    }
  }

  const int tc = tid & 15, tr = tid >> 4;
  float acc[4][4] = {};
  #pragma unroll
  for (int k4 = 0; k4 < 16; ++k4){
    float4 xr4[4];
    #pragma unroll
    for (int r = 0; r < 4; ++r)
      xr4[r] = *(float4*)&hs[(tr << 2) + r][k4 << 2];
    #pragma unroll
    for (int j = 0; j < 4; ++j){
      float4 w4 = *(float4*)&wsd[(k4 << 2) + j][tc << 2];
      #pragma unroll
      for (int r = 0; r < 4; ++r){
        float xk = (j == 0) ? xr4[r].x : (j == 1) ? xr4[r].y : (j == 2) ? xr4[r].z : xr4[r].w;
        acc[r][0] = fmaf(xk, w4.x, acc[r][0]);
        acc[r][1] = fmaf(xk, w4.y, acc[r][1]);
        acc[r][2] = fmaf(xk, w4.z, acc[r][2]);
        acc[r][3] = fmaf(xk, w4.w, acc[r][3]);
      }
    }
  }
  #pragma unroll
  for (int r = 0; r < 4; ++r){
    int row = row0 + (tr << 2) + r;
    if (row < N_NODES){
      H4 u;
      u.h[0] = __floats2half2_rn(acc[r][0], acc[r][1]);
      u.h[1] = __floats2half2_rn(acc[r][2], acc[r][3]);
      *(float2*)&h23h[(size_t)row * 64 + (tc << 2)] = u.f;
    }
  }
}

// ------- layers 2&3 aggregation: 2 nodes/wave, 16B/lane, relu + linear + var -------
__global__ __launch_bounds__(256) void k_agg23(const int* __restrict__ rowptr,
   const int* __restrict__ srcs, const __half* __restrict__ h23,
   const float2* __restrict__ es23, float2* __restrict__ edinv2,
   const float* __restrict__ ed3,
   const float* __restrict__ b2, const float* __restrict__ b3,
   const float* __restrict__ Wlin, const float* __restrict__ blin,
   float* __restrict__ mean_out, float* __restrict__ var_out){
  __shared__ float sWl[D_OUTF * D_OUTF];
  int t = threadIdx.x, lane = t & 63, wv = t >> 6;
  int nh = lane >> 5, sub = lane & 31;
  int slot2 = sub >> 3, cg = sub & 7;
  int layer = cg >> 2;                 // cg 0-3: layer2 (ch 0-31), cg 4-7: layer3 (ch 32-63)
  unsigned coff = cg << 4;
  for (int idx = t; idx < D_OUTF * D_OUTF; idx += 256) sWl[idx] = Wlin[idx];
  __syncthreads();

  int node = blockIdx.x * 8 + wv * 2 + nh;
  int beg = rowptr[node], end = rowptr[node + 1];
  int len = end - beg;
  int lenO = __shfl_xor(len, 32, 64);
  int lenmax = len > lenO ? len : lenO;
  int fallback = (len > 0) ? end - 1 : 0;
  float edv = layer ? ed3[node] : edinv2[node].x;
  float4 aL = {0,0,0,0}, aH = {0,0,0,0};
  float ss = 0.f;
  for (int off = 0; off < lenmax; off += 16){
    int sA[4]; float4 vr[4]; float p[4];
    #pragma unroll
    for (int u = 0; u < 4; ++u){
      int idx = beg + off + (u << 2) + slot2;
      sA[u] = srcs[idx < end ? idx : fallback];
    }
    #pragma unroll
    for (int u = 0; u < 4; ++u)
      vr[u] = *(const float4*)((const char*)h23 + ((unsigned)sA[u] << 7) + coff);
    #pragma unroll
    for (int u = 0; u < 4; ++u){
      float2 e2 = *(const float2*)((const char*)es23 + ((unsigned)sA[u] << 3));
      float esv = layer ? e2.y : e2.x;
      float e = __expf(leaky_relu(esv + edv));
      p[u] = ((off + (u << 2) + slot2) < len) ? e : 0.f;
    }
    #pragma unroll
    for (int u = 0; u < 4; ++u){
      ss += p[u];
      H8 hh; hh.f = vr[u];
      float2 c0 = __half22float2(hh.h[0]);
      float2 c1 = __half22float2(hh.h[1]);
      float2 c2 = __half22float2(hh.h[2]);
      float2 c3 = __half22float2(hh.h[3]);
      aL.x = fmaf(p[u], c0.x, aL.x); aL.y = fmaf(p[u], c0.y, aL.y);
      aL.z = fmaf(p[u], c1.x, aL.z); aL.w = fmaf(p[u], c1.y, aL.w);
      aH.x = fmaf(p[u], c2.x, aH.x); aH.y = fmaf(p[u], c2.y, aH.y);
      aH.z = fmaf(p[u], c3.x, aH.z); aH.w = fmaf(p[u], c3.y, aH.w);
    }
  }
  #pragma unroll
  for (int off = 8; off <= 16; off <<= 1){
    aL.x += __shfl_xor(aL.x, off, 64); aL.y += __shfl_xor(aL.y, off, 64);
    aL.z += __shfl_xor(aL.z, off, 64); aL.w += __shfl_xor(aL.w, off, 64);
    aH.x += __shfl_xor(aH.x, off, 64); aH.y += __shfl_xor(aH.y, off, 64);
    aH.z += __shfl_xor(aH.z, off, 64); aH.w += __shfl_xor(aH.w, off, 64);
    ss   += __shfl_xor(ss,   off, 64);
  }

  // layer-3 self loop (gated to layer lanes; per-half node scalars)
  {
    float psr = __expf(leaky_relu(es23[node].y + ed3[node]));
    float psg = layer ? psr : 0.f;
    H8 hh; hh.f = *(const float4*)((const char*)h23 + ((unsigned)node << 7) + coff);
    float2 c0 = __half22float2(hh.h[0]);
    float2 c1 = __half22float2(hh.h[1]);
    float2 c2 = __half22float2(hh.h[2]);
    float2 c3 = __half22float2(hh.h[3]);
    aL.x = fmaf(psg, c0.x, aL.x); aL.y = fmaf(psg, c0.y, aL.y);
    aL.z = fmaf(psg, c1.x, aL.z); aL.w = fmaf(psg, c1.y, aL.w);
    aH.x = fmaf(psg, c2.x, aH.x); aH.y = fmaf(psg, c2.y, aH.y);
    aH.z = fmaf(psg, c3.x, aH.z); aH.w = fmaf(psg, c3.y, aH.w);
    ss += psg;
  }
  float inv = 1.f / (ss + 1e-16f);

  float m0=0,m1=0,m2=0,m3=0,m4=0,m5=0,m6=0,m7=0;
  if (!layer){
    int ch0 = cg << 3;
    float4 bA = *(const float4*)&b2[ch0];
    float4 bB = *(const float4*)&b2[ch0 + 4];
    m0 = aL.x * inv + bA.x; m0 = m0 > 0.f ? m0 : 0.f;
    m1 = aL.y * inv + bA.y; m1 = m1 > 0.f ? m1 : 0.f;
    m2 = aL.z * inv + bA.z; m2 = m2 > 0.f ? m2 : 0.f;
    m3 = aL.w * inv + bA.w; m3 = m3 > 0.f ? m3 : 0.f;
    m4 = aH.x * inv + bB.x; m4 = m4 > 0.f ? m4 : 0.f;
    m5 = aH.y * inv + bB.y; m5 = m5 > 0.f ? m5 : 0.f;
    m6 = aH.z * inv + bB.z; m6 = m6 > 0.f ? m6 : 0.f;
    m7 = aH.w * inv + bB.w; m7 = m7 > 0.f ? m7 : 0.f;
  } else if (slot2 == 0){
    int ch0 = (cg & 3) << 3;
    float4 bA = *(const float4*)&b3[ch0];
    float4 bB = *(const float4*)&b3[ch0 + 4];
    float4 oA = { aL.x * inv + bA.x, aL.y * inv + bA.y, aL.z * inv + bA.z, aL.w * inv + bA.w };
    float4 oB = { aH.x * inv + bB.x, aH.y * inv + bB.y, aH.z * inv + bB.z, aH.w * inv + bB.w };
    *(float4*)&var_out[(size_t)node * D_OUTF + ch0]     = oA;
    *(float4*)&var_out[(size_t)node * D_OUTF + ch0 + 4] = oB;
  }

  // final linear on mean: out channel c = sub; m regs live on lanes (nh*32 + cgs), cgs 0-3
  {
    int c = sub;
    int lbase = lane & 32;
    float o = blin[c];
    #pragma unroll
    for (int cgs = 0; cgs < 4; ++cgs){
      int sl = lbase | cgs;
      float q0 = __shfl(m0, sl, 64), q1 = __shfl(m1, sl, 64);
      float q2 = __shfl(m2, sl, 64), q3 = __shfl(m3, sl, 64);
      float q4 = __shfl(m4, sl, 64), q5 = __shfl(m5, sl, 64);
      float q6 = __shfl(m6, sl, 64), q7 = __shfl(m7, sl, 64);
      int j0 = cgs << 3;
      o = fmaf(q0, sWl[(j0+0) * D_OUTF + c], o);
      o = fmaf(q1, sWl[(j0+1) * D_OUTF + c], o);
      o = fmaf(q2, sWl[(j0+2) * D_OUTF + c], o);
      o = fmaf(q3, sWl[(j0+3) * D_OUTF + c], o);
      o = fmaf(q4, sWl[(j0+4) * D_OUTF + c], o);
      o = fmaf(q5, sWl[(j0+5) * D_OUTF + c], o);
      o = fmaf(q6, sWl[(j0+6) * D_OUTF + c], o);
      o = fmaf(q7, sWl[(j0+7) * D_OUTF + c], o);
    }
    mean_out[(size_t)node * D_OUTF + c] = o;
  }
  if (sub == 0) edinv2[node].y = inv;   // cg==0 lane of each half is layer-2
}

// ------- alpha: flat edge-parallel, coalesced write, L2-hot gathers -------
__global__ __launch_bounds__(256) void k_alpha(const int* __restrict__ src,
    const int* __restrict__ dst,
    const float2* __restrict__ es23, const float2* __restrict__ edinv2,
    float* __restrict__ alpha_out){
  int e = blockIdx.x * blockDim.x + threadIdx.x;
  if (e < N_EDGES){
    int s = src[e], d = dst[e];
    float2 ei = *(const float2*)((const char*)edinv2 + ((unsigned)d << 3));
    float esv = ((const float2*)((const char*)es23 + ((unsigned)s << 3)))->x;
    alpha_out[e] = __expf(leaky_relu(esv + ei.x)) * ei.y;
  }
}

extern "C" void kernel_launch(void* const* d_in, const int* in_sizes, int n_in,
                              void* d_out, int out_size, void* d_ws, size_t ws_size,
                              hipStream_t stream) {
  const float* x   = (const float*)d_in[0];
  const int*   ei  = (const int*)d_in[1];
  const int*   src = ei;
  const int*   dst = ei + N_EDGES;
  const float* W1  = (const float*)d_in[2];
  const float* a1s = (const float*)d_in[3];
  const float* a1d = (const float*)d_in[4];
  const float* b1  = (const float*)d_in[5];
  const float* W2  = (const float*)d_in[6];
  const float* a2s = (const float*)d_in[7];
  const float* a2d = (const float*)d_in[8];
  const float* b2  = (const float*)d_in[9];
  const float* W3  = (const float*)d_in[10];
  const float* a3s = (const float*)d_in[11];
  const float* a3d = (const float*)d_in[12];
  const float* b3  = (const float*)d_in[13];
  const float* Wl  = (const float*)d_in[14];
  const float* bl  = (const float*)d_in[15];

  float* out       = (float*)d_out;
  float* mean_out  = out;
  float* var_out   = out + (size_t)N_NODES * D_OUTF;
  float* alpha_out = out + 2 * (size_t)N_NODES * D_OUTF;

  const int NSCAN = (N_NODES + 255) / 256;       // 196

  int* deg      = (int*)d_ws;                 // N
  int* rowptr   = deg + N_NODES;              // N+1
  int* bsum     = rowptr + (N_NODES + 1);     // NSCAN
  int* rank     = bsum + NSCAN;               // E
  int* srcs     = rank + N_EDGES;             // E
  size_t ioff   = (size_t)((srcs + N_EDGES) - (int*)d_ws);
  ioff = (ioff + 3) & ~(size_t)3;             // 16B align for half tables
  __half* h1    = (__half*)((int*)d_ws + ioff);     // N*64
  __half* h1act = h1 + (size_t)N_NODES * 64;        // N*64
  __half* h23   = h1act + (size_t)N_NODES * 64;     // N*64
  float* es1    = (float*)(h23 + (size_t)N_NODES * 64);
  float* ed1    = es1 + N_NODES;
  float* ed3    = ed1 + N_NODES;
  float* prew   = ed3 + N_NODES;              // 256 floats
  float2* es23  = (float2*)(prew + 256);
  float2* edinv2= es23 + N_NODES;

  hipMemsetAsync(deg, 0, (size_t)N_NODES * sizeof(int), stream);

  k_deg   <<<(N_EDGES + 255) / 256, 256, 0, stream>>>(dst, deg, rank);
  k_scan_a<<<NSCAN, 256, 0, stream>>>(deg, bsum);
  k_scan_b<<<1, 256, 0, stream>>>(bsum, NSCAN, W2, W3, a2s, a2d, a3s, a3d, prew);
  k_scan_c<<<NSCAN, 256, 0, stream>>>(deg, bsum, rowptr);
  k_fill  <<<(N_EDGES + 255) / 256, 256, 0, stream>>>(src, dst, rowptr, rank, srcs);

  k_gemm1<<<(N_NODES + MT - 1) / MT, 256, 0, stream>>>(x, W1, a1s, a1d, h1, es1, ed1);
  k_agg1 <<<N_NODES / 8, 256, 0, stream>>>(rowptr, srcs, h1, es1, ed1, b1, h1act);
  k_gemm23<<<(N_NODES + 63) / 64, 256, 0, stream>>>(h1act, W2, W3, prew,
                                                    h23, es23, edinv2, ed3);
  k_agg23<<<N_NODES / 8, 256, 0, stream>>>(rowptr, srcs, h23, es23, edinv2, ed3,
                                           b2, b3, Wl, bl, mean_out, var_out);
  k_alpha<<<(N_EDGES + 255) / 256, 256, 0, stream>>>(src, dst, es23, edinv2, alpha_out);
}

// Round 17
// 189.878 us; speedup vs baseline: 1.2273x; 1.0026x over previous
//
#include <hip/hip_runtime.h>
#include <hip/hip_fp16.h>
#include <math.h>

#define N_NODES 50000
#define N_EDGES 800000
#define D_INF   256
#define D_HID   64
#define D_OUTF  32
#define LEAKY   0.2f

#define MT 32     // gemm1 M-tile rows
#define KB 16     // gemm1 K-step

__device__ __forceinline__ float leaky_relu(float x){ return x >= 0.f ? x : LEAKY * x; }

union H4 { __half2 h[2]; float2 f; };
union H8 { __half2 h[4]; float4 f; };

__device__ __forceinline__ float ldg_f(const float* base, unsigned byteoff){
  return *(const float*)((const char*)base + byteoff);
}

// ---------------- CSR build ----------------
__global__ void k_zero(int* __restrict__ deg){
  int i = blockIdx.x * blockDim.x + threadIdx.x;
  if (i < N_NODES) deg[i] = 0;
}

__global__ void k_deg(const int* __restrict__ dst, int* __restrict__ deg,
                      int* __restrict__ rank){
  int i = blockIdx.x * blockDim.x + threadIdx.x;
  if (i < N_EDGES) rank[i] = atomicAdd(&deg[dst[i]], 1);
}

__global__ __launch_bounds__(256) void k_scan_a(const int* __restrict__ deg, int* __restrict__ bsum){
  __shared__ int ws[4];
  int b = blockIdx.x, t = threadIdx.x, i = b * 256 + t;
  int x = (i < N_NODES) ? deg[i] : 0;
  #pragma unroll
  for (int off = 32; off; off >>= 1) x += __shfl_down(x, off, 64);
  if ((t & 63) == 0) ws[t >> 6] = x;
  __syncthreads();
  if (t == 0) bsum[b] = ws[0] + ws[1] + ws[2] + ws[3];
}

__global__ __launch_bounds__(256) void k_scan_b(int* __restrict__ bsum, int nb,
      const float* __restrict__ W2, const float* __restrict__ W3,
      const float* __restrict__ a2s, const float* __restrict__ a2d,
      const float* __restrict__ a3s, const float* __restrict__ a3d,
      float* __restrict__ prew){
  __shared__ int ws[4];
  int t = threadIdx.x, lane = t & 63, wv = t >> 6;
  int x = (t < nb) ? bsum[t] : 0;
  #pragma unroll
  for (int off = 1; off < 64; off <<= 1){
    int y = __shfl_up(x, off, 64);
    if (lane >= off) x += y;
  }
  if (lane == 63) ws[wv] = x;
  __syncthreads();
  int add = 0;
  for (int w = 0; w < wv; ++w) add += ws[w];
  x += add;
  if (t < nb) bsum[t] = x;   // inclusive

  // prew: [w2s | w2d | w3s | w3d], each 64 floats
  int vec = t >> 6, k = t & 63;
  const float* W = (vec < 2) ? W2 : W3;
  const float* a = (vec == 0) ? a2s : (vec == 1) ? a2d : (vec == 2) ? a3s : a3d;
  float s = 0.f;
  #pragma unroll 8
  for (int c = 0; c < D_OUTF; ++c) s = fmaf(W[k * D_OUTF + c], a[c], s);
  prew[t] = s;
}

__global__ __launch_bounds__(256) void k_scan_c(const int* __restrict__ deg,
        const int* __restrict__ bsum, int* __restrict__ rowptr){
  __shared__ int ws[4];
  int b = blockIdx.x, t = threadIdx.x, i = b * 256 + t;
  int lane = t & 63, wv = t >> 6;
  int x = (i < N_NODES) ? deg[i] : 0;
  #pragma unroll
  for (int off = 1; off < 64; off <<= 1){
    int y = __shfl_up(x, off, 64);
    if (lane >= off) x += y;
  }
  if (lane == 63) ws[wv] = x;
  __syncthreads();
  int add = (b > 0) ? bsum[b - 1] : 0;
  for (int w = 0; w < wv; ++w) add += ws[w];
  x += add;
  if (i < N_NODES) rowptr[i + 1] = x;
  if (b == 0 && t == 0) rowptr[0] = 0;
}

__global__ void k_fill(const int* __restrict__ src, const int* __restrict__ dst,
                       const int* __restrict__ rowptr, const int* __restrict__ rank,
                       int* __restrict__ srcs){
  int i = blockIdx.x * blockDim.x + threadIdx.x;
  if (i < N_EDGES){
    srcs[rowptr[dst[i]] + rank[i]] = src[i];
  }
}

// ------- layer 1 GEMM: h1 = x@W1, 32-row tiles, 2x4 per thread (2x waves) -------
__global__ __launch_bounds__(256) void k_gemm1(const float* __restrict__ x,
        const float* __restrict__ W1,
        const float* __restrict__ a_src, const float* __restrict__ a_dst,
        __half* __restrict__ h1h, float* __restrict__ es, float* __restrict__ ed){
  __shared__ float xs[2][MT][KB + 4];     // 5.1 KiB
  __shared__ float ws[2][KB][D_HID];      // 8 KiB
  const int tid = threadIdx.x;
  const int tc  = tid & 15;               // col group: 4tc..4tc+3
  const int tr  = tid >> 4;               // row group: rows 2tr, 2tr+1
  const int row0 = blockIdx.x * MT;

  // x loader: threads 0..127, one float4 each (32 rows x 16 floats)
  const int lxr = tid >> 2;               // 0..31 (for tid<128)
  const int lxp = (tid & 3) << 2;
  const int gxrow = row0 + lxr;
  const bool xok = (tid < 128) && (gxrow < N_NODES);
  const float* xbase = x + (size_t)gxrow * D_INF + lxp;
  // w loader: all 256 threads, one float4 each (16 x 64 floats)
  const int lwr = tid >> 4;
  const int lwp = (tid & 15) << 2;
  const float* wbase = W1 + lwr * D_HID + lwp;

  float4 xv = xok ? *(const float4*)xbase : make_float4(0.f,0.f,0.f,0.f);
  float4 wv = *(const float4*)wbase;
  if (tid < 128) *(float4*)&xs[0][lxr][lxp] = xv;
  *(float4*)&ws[0][lwr][lwp] = wv;
  __syncthreads();

  float acc[2][4] = {};
  int b = 0;
  #pragma unroll 1
  for (int ks = 0; ks < D_INF / KB; ++ks){
    if (ks < D_INF / KB - 1){
      xv = xok ? *(const float4*)(xbase + (ks + 1) * KB) : make_float4(0.f,0.f,0.f,0.f);
      wv = *(const float4*)(wbase + (size_t)(ks + 1) * KB * D_HID);
    }
    #pragma unroll
    for (int k4 = 0; k4 < KB / 4; ++k4){
      float4 xr4[2];
      #pragma unroll
      for (int r = 0; r < 2; ++r)
        xr4[r] = *(float4*)&xs[b][(tr << 1) + r][k4 << 2];
      #pragma unroll
      for (int j = 0; j < 4; ++j){
        float4 w4 = *(float4*)&ws[b][(k4 << 2) + j][tc << 2];
        #pragma unroll
        for (int r = 0; r < 2; ++r){
          float xk = (j == 0) ? xr4[r].x : (j == 1) ? xr4[r].y : (j == 2) ? xr4[r].z : xr4[r].w;
          acc[r][0] = fmaf(xk, w4.x, acc[r][0]);
          acc[r][1] = fmaf(xk, w4.y, acc[r][1]);
          acc[r][2] = fmaf(xk, w4.z, acc[r][2]);
          acc[r][3] = fmaf(xk, w4.w, acc[r][3]);
        }
      }
    }
    if (ks < D_INF / KB - 1){
      if (tid < 128) *(float4*)&xs[b ^ 1][lxr][lxp] = xv;
      *(float4*)&ws[b ^ 1][lwr][lwp] = wv;
    }
    __syncthreads();
    b ^= 1;
  }

  float as0 = a_src[tc << 2], as1 = a_src[(tc << 2) + 1],
        as2 = a_src[(tc << 2) + 2], as3 = a_src[(tc << 2) + 3];
  float ad0 = a_dst[tc << 2], ad1 = a_dst[(tc << 2) + 1],
        ad2 = a_dst[(tc << 2) + 2], ad3 = a_dst[(tc << 2) + 3];
  #pragma unroll
  for (int r = 0; r < 2; ++r){
    int row = row0 + (tr << 1) + r;
    float ps = acc[r][0]*as0 + acc[r][1]*as1 + acc[r][2]*as2 + acc[r][3]*as3;
    float pd = acc[r][0]*ad0 + acc[r][1]*ad1 + acc[r][2]*ad2 + acc[r][3]*ad3;
    #pragma unroll
    for (int off = 1; off < 16; off <<= 1){
      ps += __shfl_xor(ps, off, 64);
      pd += __shfl_xor(pd, off, 64);
    }
    if (row < N_NODES){
      H4 u;
      u.h[0] = __floats2half2_rn(acc[r][0], acc[r][1]);
      u.h[1] = __floats2half2_rn(acc[r][2], acc[r][3]);
      *(float2*)&h1h[(size_t)row * D_HID + (tc << 2)] = u.f;
      if (tc == 0){ es[row] = ps; ed[row] = pd; }
    }
  }
}

// ------- layer 1 aggregation: 2 nodes/wave, 16B/lane, stride 16/node, bias + ELU -------
__global__ __launch_bounds__(256) void k_agg1(const int* __restrict__ rowptr,
      const int* __restrict__ srcs, const __half* __restrict__ h1,
      const float* __restrict__ es, const float* __restrict__ ed,
      const float* __restrict__ b1, __half* __restrict__ h1act){
  int t = threadIdx.x, lane = t & 63, wv = t >> 6;
  int nh = lane >> 5, sub = lane & 31;
  int slot2 = sub >> 3, cg = sub & 7;      // 4 row-slots x 8 lanes/row per half-wave
  unsigned coff = cg << 4;                 // 16B within 128B row

  int node = blockIdx.x * 8 + wv * 2 + nh;
  int beg = rowptr[node], end = rowptr[node + 1];
  int len = end - beg;
  int lenO = __shfl_xor(len, 32, 64);
  int lenmax = len > lenO ? len : lenO;
  int fallback = (len > 0) ? end - 1 : 0;
  float edv = ed[node];
  float4 aL = {0,0,0,0}, aH = {0,0,0,0};
  float ss = 0.f;
  for (int off = 0; off < lenmax; off += 16){
    int sA[4]; float4 vr[4]; float p[4];
    #pragma unroll
    for (int u = 0; u < 4; ++u){
      int idx = beg + off + (u << 2) + slot2;
      sA[u] = srcs[idx < end ? idx : fallback];
    }
    #pragma unroll
    for (int u = 0; u < 4; ++u)
      vr[u] = *(const float4*)((const char*)h1 + ((unsigned)sA[u] << 7) + coff);
    #pragma unroll
    for (int u = 0; u < 4; ++u){
      float e = __expf(leaky_relu(ldg_f(es, (unsigned)sA[u] << 2) + edv));
      p[u] = ((off + (u << 2) + slot2) < len) ? e : 0.f;
    }
    #pragma unroll
    for (int u = 0; u < 4; ++u){
      ss += p[u];
      H8 hh; hh.f = vr[u];
      float2 c0 = __half22float2(hh.h[0]);
      float2 c1 = __half22float2(hh.h[1]);
      float2 c2 = __half22float2(hh.h[2]);
      float2 c3 = __half22float2(hh.h[3]);
      aL.x = fmaf(p[u], c0.x, aL.x); aL.y = fmaf(p[u], c0.y, aL.y);
      aL.z = fmaf(p[u], c1.x, aL.z); aL.w = fmaf(p[u], c1.y, aL.w);
      aH.x = fmaf(p[u], c2.x, aH.x); aH.y = fmaf(p[u], c2.y, aH.y);
      aH.z = fmaf(p[u], c3.x, aH.z); aH.w = fmaf(p[u], c3.y, aH.w);
    }
  }
  // reduce across the 4 slots of each half-wave (lane bits 3,4 only)
  #pragma unroll
  for (int off = 8; off <= 16; off <<= 1){
    aL.x += __shfl_xor(aL.x, off, 64); aL.y += __shfl_xor(aL.y, off, 64);
    aL.z += __shfl_xor(aL.z, off, 64); aL.w += __shfl_xor(aL.w, off, 64);
    aH.x += __shfl_xor(aH.x, off, 64); aH.y += __shfl_xor(aH.y, off, 64);
    aH.z += __shfl_xor(aH.z, off, 64); aH.w += __shfl_xor(aH.w, off, 64);
    ss   += __shfl_xor(ss,   off, 64);
  }
  if (slot2 == 0){
    float inv = 1.f / (ss + 1e-16f);
    int ch0 = cg << 3;
    float4 bA = *(const float4*)&b1[ch0];
    float4 bB = *(const float4*)&b1[ch0 + 4];
    float v0 = aL.x * inv + bA.x; v0 = v0 > 0.f ? v0 : expm1f(v0);
    float v1 = aL.y * inv + bA.y; v1 = v1 > 0.f ? v1 : expm1f(v1);
    float v2 = aL.z * inv + bA.z; v2 = v2 > 0.f ? v2 : expm1f(v2);
    float v3 = aL.w * inv + bA.w; v3 = v3 > 0.f ? v3 : expm1f(v3);
    float v4 = aH.x * inv + bB.x; v4 = v4 > 0.f ? v4 : expm1f(v4);
    float v5 = aH.y * inv + bB.y; v5 = v5 > 0.f ? v5 : expm1f(v5);
    float v6 = aH.z * inv + bB.z; v6 = v6 > 0.f ? v6 : expm1f(v6);
    float v7 = aH.w * inv + bB.w; v7 = v7 > 0.f ? v7 : expm1f(v7);
    H8 o;
    o.h[0] = __floats2half2_rn(v0, v1);
    o.h[1] = __floats2half2_rn(v2, v3);
    o.h[2] = __floats2half2_rn(v4, v5);
    o.h[3] = __floats2half2_rn(v6, v7);
    *(float4*)&h1act[(size_t)node * D_HID + ch0] = o.f;
  }
}

// ---- dense GEMM: h23 = h1act @ [W2|W3] -> fp16, + fused attention dots ----
__global__ __launch_bounds__(256) void k_gemm23(const __half* __restrict__ h1acth,
        const float* __restrict__ W2, const float* __restrict__ W3,
        const float* __restrict__ prew,
        __half* __restrict__ h23h, float2* __restrict__ es23,
        float2* __restrict__ edinv2, float* __restrict__ ed3){
  __shared__ float hs[64][68];
  __shared__ float wsd[64][64];
  __shared__ float sprew[256];
  const int tid = threadIdx.x;
  const int row0 = blockIdx.x * 64;

  {
    int r = tid >> 2, cg = tid & 3;
    int grow = row0 + r;
    bool ok = grow < N_NODES;
    const float4* hrow = (const float4*)(h1acth + (size_t)grow * D_HID + cg * 16);
    H8 q0, q1;
    q0.f = ok ? hrow[0] : make_float4(0,0,0,0);
    q1.f = ok ? hrow[1] : make_float4(0,0,0,0);
    float* dsth = &hs[r][cg * 16];
    #pragma unroll
    for (int j = 0; j < 4; ++j){
      float2 f = __half22float2(q0.h[j]);
      dsth[j * 2] = f.x; dsth[j * 2 + 1] = f.y;
    }
    #pragma unroll
    for (int j = 0; j < 4; ++j){
      float2 f = __half22float2(q1.h[j]);
      dsth[8 + j * 2] = f.x; dsth[8 + j * 2 + 1] = f.y;
    }
    int k = tid >> 2;
    const float* Wsrc = (cg < 2) ? W2 : W3;
    int cbase = (cg & 1) * 16;
    float4* dstw = (float4*)&wsd[k][cg * 16];
    const float4* srcw = (const float4*)&Wsrc[k * D_OUTF + cbase];
    #pragma unroll
    for (int j = 0; j < 4; ++j) dstw[j] = srcw[j];
    sprew[tid] = prew[tid];
  }
  __syncthreads();

  // fused attention-dot scalars: row r by 4 lanes (16-ch quarters)
  {
    int r = tid >> 2, q = tid & 3, row = row0 + r;
    float d0 = 0.f, d1 = 0.f, d2 = 0.f, d3 = 0.f;
    #pragma unroll
    for (int k = 0; k < 16; ++k){
      float hval = hs[r][(q << 4) + k];
      d0 = fmaf(hval, sprew[(q << 4) + k], d0);
      d1 = fmaf(hval, sprew[64 + (q << 4) + k], d1);
      d2 = fmaf(hval, sprew[128 + (q << 4) + k], d2);
      d3 = fmaf(hval, sprew[192 + (q << 4) + k], d3);
    }
    #pragma unroll
    for (int off = 1; off < 4; off <<= 1){
      d0 += __shfl_xor(d0, off, 64);
      d1 += __shfl_xor(d1, off, 64);
      d2 += __shfl_xor(d2, off, 64);
      d3 += __shfl_xor(d3, off, 64);
    }
    if (q == 0 && row < N_NODES){
      es23[row] = make_float2(d0, d2);
      edinv2[row].x = d1;
      ed3[row] = d3;
    }
  }

  const int tc = tid & 15, tr = tid >> 4;
  float acc[4][4] = {};
  #pragma unroll
  for (int k4 = 0; k4 < 16; ++k4){
    float4 xr4[4];
    #pragma unroll
    for (int r = 0; r < 4; ++r)
      xr4[r] = *(float4*)&hs[(tr << 2) + r][k4 << 2];
    #pragma unroll
    for (int j = 0; j < 4; ++j){
      float4 w4 = *(float4*)&wsd[(k4 << 2) + j][tc << 2];
      #pragma unroll
      for (int r = 0; r < 4; ++r){
        float xk = (j == 0) ? xr4[r].x : (j == 1) ? xr4[r].y : (j == 2) ? xr4[r].z : xr4[r].w;
        acc[r][0] = fmaf(xk, w4.x, acc[r][0]);
        acc[r][1] = fmaf(xk, w4.y, acc[r][1]);
        acc[r][2] = fmaf(xk, w4.z, acc[r][2]);
        acc[r][3] = fmaf(xk, w4.w, acc[r][3]);
      }
    }
  }
  #pragma unroll
  for (int r = 0; r < 4; ++r){
    int row = row0 + (tr << 2) + r;
    if (row < N_NODES){
      H4 u;
      u.h[0] = __floats2half2_rn(acc[r][0], acc[r][1]);
      u.h[1] = __floats2half2_rn(acc[r][2], acc[r][3]);
      *(float2*)&h23h[(size_t)row * 64 + (tc << 2)] = u.f;
    }
  }
}

// ------- layers 2&3 aggregation: 2 nodes/wave, 16B/lane, relu + linear + var -------
__global__ __launch_bounds__(256) void k_agg23(const int* __restrict__ rowptr,
   const int* __restrict__ srcs, const __half* __restrict__ h23,
   const float2* __restrict__ es23, float2* __restrict__ edinv2,
   const float* __restrict__ ed3,
   const float* __restrict__ b2, const float* __restrict__ b3,
   const float* __restrict__ Wlin, const float* __restrict__ blin,
   float* __restrict__ mean_out, float* __restrict__ var_out){
  __shared__ float sWl[D_OUTF * D_OUTF];
  int t = threadIdx.x, lane = t & 63, wv = t >> 6;
  int nh = lane >> 5, sub = lane & 31;
  int slot2 = sub >> 3, cg = sub & 7;
  int layer = cg >> 2;                 // cg 0-3: layer2 (ch 0-31), cg 4-7: layer3 (ch 32-63)
  unsigned coff = cg << 4;
  for (int idx = t; idx < D_OUTF * D_OUTF; idx += 256) sWl[idx] = Wlin[idx];
  __syncthreads();

  int node = blockIdx.x * 8 + wv * 2 + nh;
  int beg = rowptr[node], end = rowptr[node + 1];
  int len = end - beg;
  int lenO = __shfl_xor(len, 32, 64);
  int lenmax = len > lenO ? len : lenO;
  int fallback = (len > 0) ? end - 1 : 0;
  float edv = layer ? ed3[node] : edinv2[node].x;
  float4 aL = {0,0,0,0}, aH = {0,0,0,0};
  float ss = 0.f;
  for (int off = 0; off < lenmax; off += 16){
    int sA[4]; float4 vr[4]; float p[4];
    #pragma unroll
    for (int u = 0; u < 4; ++u){
      int idx = beg + off + (u << 2) + slot2;
      sA[u] = srcs[idx < end ? idx : fallback];
    }
    #pragma unroll
    for (int u = 0; u < 4; ++u)
      vr[u] = *(const float4*)((const char*)h23 + ((unsigned)sA[u] << 7) + coff);
    #pragma unroll
    for (int u = 0; u < 4; ++u){
      float2 e2 = *(const float2*)((const char*)es23 + ((unsigned)sA[u] << 3));
      float esv = layer ? e2.y : e2.x;
      float e = __expf(leaky_relu(esv + edv));
      p[u] = ((off + (u << 2) + slot2) < len) ? e : 0.f;
    }
    #pragma unroll
    for (int u = 0; u < 4; ++u){
      ss += p[u];
      H8 hh; hh.f = vr[u];
      float2 c0 = __half22float2(hh.h[0]);
      float2 c1 = __half22float2(hh.h[1]);
      float2 c2 = __half22float2(hh.h[2]);
      float2 c3 = __half22float2(hh.h[3]);
      aL.x = fmaf(p[u], c0.x, aL.x); aL.y = fmaf(p[u], c0.y, aL.y);
      aL.z = fmaf(p[u], c1.x, aL.z); aL.w = fmaf(p[u], c1.y, aL.w);
      aH.x = fmaf(p[u], c2.x, aH.x); aH.y = fmaf(p[u], c2.y, aH.y);
      aH.z = fmaf(p[u], c3.x, aH.z); aH.w = fmaf(p[u], c3.y, aH.w);
    }
  }
  #pragma unroll
  for (int off = 8; off <= 16; off <<= 1){
    aL.x += __shfl_xor(aL.x, off, 64); aL.y += __shfl_xor(aL.y, off, 64);
    aL.z += __shfl_xor(aL.z, off, 64); aL.w += __shfl_xor(aL.w, off, 64);
    aH.x += __shfl_xor(aH.x, off, 64); aH.y += __shfl_xor(aH.y, off, 64);
    aH.z += __shfl_xor(aH.z, off, 64); aH.w += __shfl_xor(aH.w, off, 64);
    ss   += __shfl_xor(ss,   off, 64);
  }

  // layer-3 self loop (gated to layer lanes; per-half node scalars)
  {
    float psr = __expf(leaky_relu(es23[node].y + ed3[node]));
    float psg = layer ? psr : 0.f;
    H8 hh; hh.f = *(const float4*)((const char*)h23 + ((unsigned)node << 7) + coff);
    float2 c0 = __half22float2(hh.h[0]);
    float2 c1 = __half22float2(hh.h[1]);
    float2 c2 = __half22float2(hh.h[2]);
    float2 c3 = __half22float2(hh.h[3]);
    aL.x = fmaf(psg, c0.x, aL.x); aL.y = fmaf(psg, c0.y, aL.y);
    aL.z = fmaf(psg, c1.x, aL.z); aL.w = fmaf(psg, c1.y, aL.w);
    aH.x = fmaf(psg, c2.x, aH.x); aH.y = fmaf(psg, c2.y, aH.y);
    aH.z = fmaf(psg, c3.x, aH.z); aH.w = fmaf(psg, c3.y, aH.w);
    ss += psg;
  }
  float inv = 1.f / (ss + 1e-16f);

  float m0=0,m1=0,m2=0,m3=0,m4=0,m5=0,m6=0,m7=0;
  if (!layer){
    int ch0 = cg << 3;
    float4 bA = *(const float4*)&b2[ch0];
    float4 bB = *(const float4*)&b2[ch0 + 4];
    m0 = aL.x * inv + bA.x; m0 = m0 > 0.f ? m0 : 0.f;
    m1 = aL.y * inv + bA.y; m1 = m1 > 0.f ? m1 : 0.f;
    m2 = aL.z * inv + bA.z; m2 = m2 > 0.f ? m2 : 0.f;
    m3 = aL.w * inv + bA.w; m3 = m3 > 0.f ? m3 : 0.f;
    m4 = aH.x * inv + bB.x; m4 = m4 > 0.f ? m4 : 0.f;
    m5 = aH.y * inv + bB.y; m5 = m5 > 0.f ? m5 : 0.f;
    m6 = aH.z * inv + bB.z; m6 = m6 > 0.f ? m6 : 0.f;
    m7 = aH.w * inv + bB.w; m7 = m7 > 0.f ? m7 : 0.f;
  } else if (slot2 == 0){
    int ch0 = (cg & 3) << 3;
    float4 bA = *(const float4*)&b3[ch0];
    float4 bB = *(const float4*)&b3[ch0 + 4];
    float4 oA = { aL.x * inv + bA.x, aL.y * inv + bA.y, aL.z * inv + bA.z, aL.w * inv + bA.w };
    float4 oB = { aH.x * inv + bB.x, aH.y * inv + bB.y, aH.z * inv + bB.z, aH.w * inv + bB.w };
    *(float4*)&var_out[(size_t)node * D_OUTF + ch0]     = oA;
    *(float4*)&var_out[(size_t)node * D_OUTF + ch0 + 4] = oB;
  }

  // final linear on mean: out channel c = sub; m regs live on lanes (nh*32 + cgs), cgs 0-3
  {
    int c = sub;
    int lbase = lane & 32;
    float o = blin[c];
    #pragma unroll
    for (int cgs = 0; cgs < 4; ++cgs){
      int sl = lbase | cgs;
      float q0 = __shfl(m0, sl, 64), q1 = __shfl(m1, sl, 64);
      float q2 = __shfl(m2, sl, 64), q3 = __shfl(m3, sl, 64);
      float q4 = __shfl(m4, sl, 64), q5 = __shfl(m5, sl, 64);
      float q6 = __shfl(m6, sl, 64), q7 = __shfl(m7, sl, 64);
      int j0 = cgs << 3;
      o = fmaf(q0, sWl[(j0+0) * D_OUTF + c], o);
      o = fmaf(q1, sWl[(j0+1) * D_OUTF + c], o);
      o = fmaf(q2, sWl[(j0+2) * D_OUTF + c], o);
      o = fmaf(q3, sWl[(j0+3) * D_OUTF + c], o);
      o = fmaf(q4, sWl[(j0+4) * D_OUTF + c], o);
      o = fmaf(q5, sWl[(j0+5) * D_OUTF + c], o);
      o = fmaf(q6, sWl[(j0+6) * D_OUTF + c], o);
      o = fmaf(q7, sWl[(j0+7) * D_OUTF + c], o);
    }
    mean_out[(size_t)node * D_OUTF + c] = o;
  }
  if (sub == 0) edinv2[node].y = inv;   // cg==0 lane of each half is layer-2
}

// ------- alpha: flat edge-parallel, coalesced write, L2-hot gathers -------
__global__ __launch_bounds__(256) void k_alpha(const int* __restrict__ src,
    const int* __restrict__ dst,
    const float2* __restrict__ es23, const float2* __restrict__ edinv2,
    float* __restrict__ alpha_out){
  int e = blockIdx.x * blockDim.x + threadIdx.x;
  if (e < N_EDGES){
    int s = src[e], d = dst[e];
    float2 ei = *(const float2*)((const char*)edinv2 + ((unsigned)d << 3));
    float esv = ((const float2*)((const char*)es23 + ((unsigned)s << 3)))->x;
    alpha_out[e] = __expf(leaky_relu(esv + ei.x)) * ei.y;
  }
}

extern "C" void kernel_launch(void* const* d_in, const int* in_sizes, int n_in,
                              void* d_out, int out_size, void* d_ws, size_t ws_size,
                              hipStream_t stream) {
  const float* x   = (const float*)d_in[0];
  const int*   ei  = (const int*)d_in[1];
  const int*   src = ei;
  const int*   dst = ei + N_EDGES;
  const float* W1  = (const float*)d_in[2];
  const float* a1s = (const float*)d_in[3];
  const float* a1d = (const float*)d_in[4];
  const float* b1  = (const float*)d_in[5];
  const float* W2  = (const float*)d_in[6];
  const float* a2s = (const float*)d_in[7];
  const float* a2d = (const float*)d_in[8];
  const float* b2  = (const float*)d_in[9];
  const float* W3  = (const float*)d_in[10];
  const float* a3s = (const float*)d_in[11];
  const float* a3d = (const float*)d_in[12];
  const float* b3  = (const float*)d_in[13];
  const float* Wl  = (const float*)d_in[14];
  const float* bl  = (const float*)d_in[15];

  float* out       = (float*)d_out;
  float* mean_out  = out;
  float* var_out   = out + (size_t)N_NODES * D_OUTF;
  float* alpha_out = out + 2 * (size_t)N_NODES * D_OUTF;

  const int NSCAN = (N_NODES + 255) / 256;       // 196

  int* deg      = (int*)d_ws;                 // N
  int* rowptr   = deg + N_NODES;              // N+1
  int* bsum     = rowptr + (N_NODES + 1);     // NSCAN
  int* rank     = bsum + NSCAN;               // E
  int* srcs     = rank + N_EDGES;             // E
  size_t ioff   = (size_t)((srcs + N_EDGES) - (int*)d_ws);
  ioff = (ioff + 3) & ~(size_t)3;             // 16B align for half tables
  __half* h1    = (__half*)((int*)d_ws + ioff);     // N*64
  __half* h1act = h1 + (size_t)N_NODES * 64;        // N*64
  __half* h23   = h1act + (size_t)N_NODES * 64;     // N*64
  float* es1    = (float*)(h23 + (size_t)N_NODES * 64);
  float* ed1    = es1 + N_NODES;
  float* ed3    = ed1 + N_NODES;
  float* prew   = ed3 + N_NODES;              // 256 floats
  float2* es23  = (float2*)(prew + 256);
  float2* edinv2= es23 + N_NODES;

  k_zero  <<<NSCAN, 256, 0, stream>>>(deg);
  k_deg   <<<(N_EDGES + 255) / 256, 256, 0, stream>>>(dst, deg, rank);
  k_scan_a<<<NSCAN, 256, 0, stream>>>(deg, bsum);
  k_scan_b<<<1, 256, 0, stream>>>(bsum, NSCAN, W2, W3, a2s, a2d, a3s, a3d, prew);
  k_scan_c<<<NSCAN, 256, 0, stream>>>(deg, bsum, rowptr);
  k_fill  <<<(N_EDGES + 255) / 256, 256, 0, stream>>>(src, dst, rowptr, rank, srcs);

  k_gemm1<<<(N_NODES + MT - 1) / MT, 256, 0, stream>>>(x, W1, a1s, a1d, h1, es1, ed1);
  k_agg1 <<<N_NODES / 8, 256, 0, stream>>>(rowptr, srcs, h1, es1, ed1, b1, h1act);
  k_gemm23<<<(N_NODES + 63) / 64, 256, 0, stream>>>(h1act, W2, W3, prew,
                                                    h23, es23, edinv2, ed3);
  k_agg23<<<N_NODES / 8, 256, 0, stream>>>(rowptr, srcs, h23, es23, edinv2, ed3,
                                           b2, b3, Wl, bl, mean_out, var_out);
  k_alpha<<<(N_EDGES + 255) / 256, 256, 0, stream>>>(src, dst, es23, edinv2, alpha_out);
}

// Round 18
// 173.781 us; speedup vs baseline: 1.3410x; 1.0926x over previous
//
#include <hip/hip_runtime.h>
#include <hip/hip_fp16.h>
#include <math.h>

#define N_NODES 50000
#define N_EDGES 800000
#define D_INF   256
#define D_HID   64
#define D_OUTF  32
#define LEAKY   0.2f

__device__ __forceinline__ float leaky_relu(float x){ return x >= 0.f ? x : LEAKY * x; }

union H4 { __half2 h[2]; float2 f; };
union H8 { __half2 h[4]; float4 f; };

typedef __attribute__((ext_vector_type(8))) _Float16 half8;
typedef __attribute__((ext_vector_type(4))) float f32x4;

__device__ __forceinline__ float ldg_f(const float* base, unsigned byteoff){
  return *(const float*)((const char*)base + byteoff);
}

// ---------------- CSR build ----------------
__global__ void k_zero(int* __restrict__ deg){
  int i = blockIdx.x * blockDim.x + threadIdx.x;
  if (i < N_NODES) deg[i] = 0;
}

__global__ void k_deg(const int* __restrict__ dst, int* __restrict__ deg,
                      int* __restrict__ rank){
  int i = blockIdx.x * blockDim.x + threadIdx.x;
  if (i < N_EDGES) rank[i] = atomicAdd(&deg[dst[i]], 1);
}

__global__ __launch_bounds__(256) void k_scan_a(const int* __restrict__ deg, int* __restrict__ bsum){
  __shared__ int ws[4];
  int b = blockIdx.x, t = threadIdx.x, i = b * 256 + t;
  int x = (i < N_NODES) ? deg[i] : 0;
  #pragma unroll
  for (int off = 32; off; off >>= 1) x += __shfl_down(x, off, 64);
  if ((t & 63) == 0) ws[t >> 6] = x;
  __syncthreads();
  if (t == 0) bsum[b] = ws[0] + ws[1] + ws[2] + ws[3];
}

__global__ __launch_bounds__(256) void k_scan_b(int* __restrict__ bsum, int nb,
      const float* __restrict__ W2, const float* __restrict__ W3,
      const float* __restrict__ a2s, const float* __restrict__ a2d,
      const float* __restrict__ a3s, const float* __restrict__ a3d,
      float* __restrict__ prew){
  __shared__ int ws[4];
  int t = threadIdx.x, lane = t & 63, wv = t >> 6;
  int x = (t < nb) ? bsum[t] : 0;
  #pragma unroll
  for (int off = 1; off < 64; off <<= 1){
    int y = __shfl_up(x, off, 64);
    if (lane >= off) x += y;
  }
  if (lane == 63) ws[wv] = x;
  __syncthreads();
  int add = 0;
  for (int w = 0; w < wv; ++w) add += ws[w];
  x += add;
  if (t < nb) bsum[t] = x;   // inclusive

  // prew: [w2s | w2d | w3s | w3d], each 64 floats
  int vec = t >> 6, k = t & 63;
  const float* W = (vec < 2) ? W2 : W3;
  const float* a = (vec == 0) ? a2s : (vec == 1) ? a2d : (vec == 2) ? a3s : a3d;
  float s = 0.f;
  #pragma unroll 8
  for (int c = 0; c < D_OUTF; ++c) s = fmaf(W[k * D_OUTF + c], a[c], s);
  prew[t] = s;
}

__global__ __launch_bounds__(256) void k_scan_c(const int* __restrict__ deg,
        const int* __restrict__ bsum, int* __restrict__ rowptr){
  __shared__ int ws[4];
  int b = blockIdx.x, t = threadIdx.x, i = b * 256 + t;
  int lane = t & 63, wv = t >> 6;
  int x = (i < N_NODES) ? deg[i] : 0;
  #pragma unroll
  for (int off = 1; off < 64; off <<= 1){
    int y = __shfl_up(x, off, 64);
    if (lane >= off) x += y;
  }
  if (lane == 63) ws[wv] = x;
  __syncthreads();
  int add = (b > 0) ? bsum[b - 1] : 0;
  for (int w = 0; w < wv; ++w) add += ws[w];
  x += add;
  if (i < N_NODES) rowptr[i + 1] = x;
  if (b == 0 && t == 0) rowptr[0] = 0;
}

__global__ void k_fill(const int* __restrict__ src, const int* __restrict__ dst,
                       const int* __restrict__ rowptr, const int* __restrict__ rank,
                       int* __restrict__ srcs){
  int i = blockIdx.x * blockDim.x + threadIdx.x;
  if (i < N_EDGES){
    srcs[rowptr[dst[i]] + rank[i]] = src[i];
  }
}

// ------- layer 1 GEMM via MFMA f16: h1 = x@W1, 64-row blocks, 4 waves x 16 rows -------
__global__ __launch_bounds__(256) void k_gemm1(const float* __restrict__ x,
        const float* __restrict__ W1,
        const float* __restrict__ a_src, const float* __restrict__ a_dst,
        __half* __restrict__ h1h, float* __restrict__ es, float* __restrict__ ed){
  __shared__ _Float16 wlds[64][264];      // W1^T as fp16, pad 8 halves -> 33.8 KiB
  const int tid = threadIdx.x, lane = tid & 63, w = tid >> 6;
  const int row0 = blockIdx.x * 64 + w * 16;

  // stage W1^T: wlds[n][k] = W1[k][n] (coalesced global read over n)
  for (int idx = tid; idx < 64 * 256; idx += 256){
    int n = idx & 63, k = idx >> 6;
    wlds[n][k] = (_Float16)W1[k * 64 + n];
  }
  __syncthreads();

  int arow = row0 + (lane & 15);
  if (arow >= N_NODES) arow = N_NODES - 1;          // clamp (writes guarded)
  const float* xrow = x + (size_t)arow * D_INF;
  const int klane = (lane >> 4) * 8;

  f32x4 acc[4] = {{0,0,0,0},{0,0,0,0},{0,0,0,0},{0,0,0,0}};
  #pragma unroll
  for (int ks = 0; ks < 8; ++ks){
    float4 xa = *(const float4*)(xrow + ks * 32 + klane);
    float4 xb = *(const float4*)(xrow + ks * 32 + klane + 4);
    half8 a;
    a[0] = (_Float16)xa.x; a[1] = (_Float16)xa.y; a[2] = (_Float16)xa.z; a[3] = (_Float16)xa.w;
    a[4] = (_Float16)xb.x; a[5] = (_Float16)xb.y; a[6] = (_Float16)xb.z; a[7] = (_Float16)xb.w;
    #pragma unroll
    for (int ct = 0; ct < 4; ++ct){
      half8 b = *(const half8*)&wlds[ct * 16 + (lane & 15)][ks * 32 + klane];
      acc[ct] = __builtin_amdgcn_mfma_f32_16x16x32_f16(a, b, acc[ct], 0, 0, 0);
    }
  }

  // D layout: col = lane&15 (wlds row = h1 col), row = (lane>>4)*4 + reg (x row)
  float ps[4] = {0,0,0,0}, pd[4] = {0,0,0,0};
  #pragma unroll
  for (int ct = 0; ct < 4; ++ct){
    int col = ct * 16 + (lane & 15);
    float as = a_src[col], ad = a_dst[col];
    #pragma unroll
    for (int r = 0; r < 4; ++r){
      int row = row0 + (lane >> 4) * 4 + r;
      if (row < N_NODES)
        h1h[(size_t)row * D_HID + col] = __float2half_rn(acc[ct][r]);
      ps[r] = fmaf(acc[ct][r], as, ps[r]);
      pd[r] = fmaf(acc[ct][r], ad, pd[r]);
    }
  }
  #pragma unroll
  for (int off = 1; off < 16; off <<= 1){
    #pragma unroll
    for (int r = 0; r < 4; ++r){
      ps[r] += __shfl_xor(ps[r], off, 64);
      pd[r] += __shfl_xor(pd[r], off, 64);
    }
  }
  if ((lane & 15) == 0){
    #pragma unroll
    for (int r = 0; r < 4; ++r){
      int row = row0 + (lane >> 4) * 4 + r;
      if (row < N_NODES){ es[row] = ps[r]; ed[row] = pd[r]; }
    }
  }
}

// ------- layer 1 aggregation: 2 nodes/wave, 16B/lane, stride 16/node, bias + ELU -------
__global__ __launch_bounds__(256) void k_agg1(const int* __restrict__ rowptr,
      const int* __restrict__ srcs, const __half* __restrict__ h1,
      const float* __restrict__ es, const float* __restrict__ ed,
      const float* __restrict__ b1, __half* __restrict__ h1act){
  int t = threadIdx.x, lane = t & 63, wv = t >> 6;
  int nh = lane >> 5, sub = lane & 31;
  int slot2 = sub >> 3, cg = sub & 7;      // 4 row-slots x 8 lanes/row per half-wave
  unsigned coff = cg << 4;                 // 16B within 128B row

  int node = blockIdx.x * 8 + wv * 2 + nh;
  int beg = rowptr[node], end = rowptr[node + 1];
  int len = end - beg;
  int lenO = __shfl_xor(len, 32, 64);
  int lenmax = len > lenO ? len : lenO;
  int fallback = (len > 0) ? end - 1 : 0;
  float edv = ed[node];
  float4 aL = {0,0,0,0}, aH = {0,0,0,0};
  float ss = 0.f;
  for (int off = 0; off < lenmax; off += 16){
    int sA[4]; float4 vr[4]; float p[4];
    #pragma unroll
    for (int u = 0; u < 4; ++u){
      int idx = beg + off + (u << 2) + slot2;
      sA[u] = srcs[idx < end ? idx : fallback];
    }
    #pragma unroll
    for (int u = 0; u < 4; ++u)
      vr[u] = *(const float4*)((const char*)h1 + ((unsigned)sA[u] << 7) + coff);
    #pragma unroll
    for (int u = 0; u < 4; ++u){
      float e = __expf(leaky_relu(ldg_f(es, (unsigned)sA[u] << 2) + edv));
      p[u] = ((off + (u << 2) + slot2) < len) ? e : 0.f;
    }
    #pragma unroll
    for (int u = 0; u < 4; ++u){
      ss += p[u];
      H8 hh; hh.f = vr[u];
      float2 c0 = __half22float2(hh.h[0]);
      float2 c1 = __half22float2(hh.h[1]);
      float2 c2 = __half22float2(hh.h[2]);
      float2 c3 = __half22float2(hh.h[3]);
      aL.x = fmaf(p[u], c0.x, aL.x); aL.y = fmaf(p[u], c0.y, aL.y);
      aL.z = fmaf(p[u], c1.x, aL.z); aL.w = fmaf(p[u], c1.y, aL.w);
      aH.x = fmaf(p[u], c2.x, aH.x); aH.y = fmaf(p[u], c2.y, aH.y);
      aH.z = fmaf(p[u], c3.x, aH.z); aH.w = fmaf(p[u], c3.y, aH.w);
    }
  }
  // reduce across the 4 slots of each half-wave (lane bits 3,4 only)
  #pragma unroll
  for (int off = 8; off <= 16; off <<= 1){
    aL.x += __shfl_xor(aL.x, off, 64); aL.y += __shfl_xor(aL.y, off, 64);
    aL.z += __shfl_xor(aL.z, off, 64); aL.w += __shfl_xor(aL.w, off, 64);
    aH.x += __shfl_xor(aH.x, off, 64); aH.y += __shfl_xor(aH.y, off, 64);
    aH.z += __shfl_xor(aH.z, off, 64); aH.w += __shfl_xor(aH.w, off, 64);
    ss   += __shfl_xor(ss,   off, 64);
  }
  if (slot2 == 0){
    float inv = 1.f / (ss + 1e-16f);
    int ch0 = cg << 3;
    float4 bA = *(const float4*)&b1[ch0];
    float4 bB = *(const float4*)&b1[ch0 + 4];
    float v0 = aL.x * inv + bA.x; v0 = v0 > 0.f ? v0 : expm1f(v0);
    float v1 = aL.y * inv + bA.y; v1 = v1 > 0.f ? v1 : expm1f(v1);
    float v2 = aL.z * inv + bA.z; v2 = v2 > 0.f ? v2 : expm1f(v2);
    float v3 = aL.w * inv + bA.w; v3 = v3 > 0.f ? v3 : expm1f(v3);
    float v4 = aH.x * inv + bB.x; v4 = v4 > 0.f ? v4 : expm1f(v4);
    float v5 = aH.y * inv + bB.y; v5 = v5 > 0.f ? v5 : expm1f(v5);
    float v6 = aH.z * inv + bB.z; v6 = v6 > 0.f ? v6 : expm1f(v6);
    float v7 = aH.w * inv + bB.w; v7 = v7 > 0.f ? v7 : expm1f(v7);
    H8 o;
    o.h[0] = __floats2half2_rn(v0, v1);
    o.h[1] = __floats2half2_rn(v2, v3);
    o.h[2] = __floats2half2_rn(v4, v5);
    o.h[3] = __floats2half2_rn(v6, v7);
    *(float4*)&h1act[(size_t)node * D_HID + ch0] = o.f;
  }
}

// ---- dense GEMM: h23 = h1act @ [W2|W3] -> fp16, + fused attention dots ----
__global__ __launch_bounds__(256) void k_gemm23(const __half* __restrict__ h1acth,
        const float* __restrict__ W2, const float* __restrict__ W3,
        const float* __restrict__ prew,
        __half* __restrict__ h23h, float2* __restrict__ es23,
        float2* __restrict__ edinv2, float* __restrict__ ed3){
  __shared__ float hs[64][68];
  __shared__ float wsd[64][64];
  __shared__ float sprew[256];
  const int tid = threadIdx.x;
  const int row0 = blockIdx.x * 64;

  {
    int r = tid >> 2, cg = tid & 3;
    int grow = row0 + r;
    bool ok = grow < N_NODES;
    const float4* hrow = (const float4*)(h1acth + (size_t)grow * D_HID + cg * 16);
    H8 q0, q1;
    q0.f = ok ? hrow[0] : make_float4(0,0,0,0);
    q1.f = ok ? hrow[1] : make_float4(0,0,0,0);
    float* dsth = &hs[r][cg * 16];
    #pragma unroll
    for (int j = 0; j < 4; ++j){
      float2 f = __half22float2(q0.h[j]);
      dsth[j * 2] = f.x; dsth[j * 2 + 1] = f.y;
    }
    #pragma unroll
    for (int j = 0; j < 4; ++j){
      float2 f = __half22float2(q1.h[j]);
      dsth[8 + j * 2] = f.x; dsth[8 + j * 2 + 1] = f.y;
    }
    int k = tid >> 2;
    const float* Wsrc = (cg < 2) ? W2 : W3;
    int cbase = (cg & 1) * 16;
    float4* dstw = (float4*)&wsd[k][cg * 16];
    const float4* srcw = (const float4*)&Wsrc[k * D_OUTF + cbase];
    #pragma unroll
    for (int j = 0; j < 4; ++j) dstw[j] = srcw[j];
    sprew[tid] = prew[tid];
  }
  __syncthreads();

  // fused attention-dot scalars: row r by 4 lanes (16-ch quarters)
  {
    int r = tid >> 2, q = tid & 3, row = row0 + r;
    float d0 = 0.f, d1 = 0.f, d2 = 0.f, d3 = 0.f;
    #pragma unroll
    for (int k = 0; k < 16; ++k){
      float hval = hs[r][(q << 4) + k];
      d0 = fmaf(hval, sprew[(q << 4) + k], d0);
      d1 = fmaf(hval, sprew[64 + (q << 4) + k], d1);
      d2 = fmaf(hval, sprew[128 + (q << 4) + k], d2);
      d3 = fmaf(hval, sprew[192 + (q << 4) + k], d3);
    }
    #pragma unroll
    for (int off = 1; off < 4; off <<= 1){
      d0 += __shfl_xor(d0, off, 64);
      d1 += __shfl_xor(d1, off, 64);
      d2 += __shfl_xor(d2, off, 64);
      d3 += __shfl_xor(d3, off, 64);
    }
    if (q == 0 && row < N_NODES){
      es23[row] = make_float2(d0, d2);
      edinv2[row].x = d1;
      ed3[row] = d3;
    }
  }

  const int tc = tid & 15, tr = tid >> 4;
  float acc[4][4] = {};
  #pragma unroll
  for (int k4 = 0; k4 < 16; ++k4){
    float4 xr4[4];
    #pragma unroll
    for (int r = 0; r < 4; ++r)
      xr4[r] = *(float4*)&hs[(tr << 2) + r][k4 << 2];
    #pragma unroll
    for (int j = 0; j < 4; ++j){
      float4 w4 = *(float4*)&wsd[(k4 << 2) + j][tc << 2];
      #pragma unroll
      for (int r = 0; r < 4; ++r){
        float xk = (j == 0) ? xr4[r].x : (j == 1) ? xr4[r].y : (j == 2) ? xr4[r].z : xr4[r].w;
        acc[r][0] = fmaf(xk, w4.x, acc[r][0]);
        acc[r][1] = fmaf(xk, w4.y, acc[r][1]);
        acc[r][2] = fmaf(xk, w4.z, acc[r][2]);
        acc[r][3] = fmaf(xk, w4.w, acc[r][3]);
      }
    }
  }
  #pragma unroll
  for (int r = 0; r < 4; ++r){
    int row = row0 + (tr << 2) + r;
    if (row < N_NODES){
      H4 u;
      u.h[0] = __floats2half2_rn(acc[r][0], acc[r][1]);
      u.h[1] = __floats2half2_rn(acc[r][2], acc[r][3]);
      *(float2*)&h23h[(size_t)row * 64 + (tc << 2)] = u.f;
    }
  }
}

// ------- layers 2&3 aggregation: 2 nodes/wave, 16B/lane, relu + linear + var -------
__global__ __launch_bounds__(256) void k_agg23(const int* __restrict__ rowptr,
   const int* __restrict__ srcs, const __half* __restrict__ h23,
   const float2* __restrict__ es23, float2* __restrict__ edinv2,
   const float* __restrict__ ed3,
   const float* __restrict__ b2, const float* __restrict__ b3,
   const float* __restrict__ Wlin, const float* __restrict__ blin,
   float* __restrict__ mean_out, float* __restrict__ var_out){
  __shared__ float sWl[D_OUTF * D_OUTF];
  int t = threadIdx.x, lane = t & 63, wv = t >> 6;
  int nh = lane >> 5, sub = lane & 31;
  int slot2 = sub >> 3, cg = sub & 7;
  int layer = cg >> 2;                 // cg 0-3: layer2 (ch 0-31), cg 4-7: layer3 (ch 32-63)
  unsigned coff = cg << 4;
  for (int idx = t; idx < D_OUTF * D_OUTF; idx += 256) sWl[idx] = Wlin[idx];
  __syncthreads();

  int node = blockIdx.x * 8 + wv * 2 + nh;
  int beg = rowptr[node], end = rowptr[node + 1];
  int len = end - beg;
  int lenO = __shfl_xor(len, 32, 64);
  int lenmax = len > lenO ? len : lenO;
  int fallback = (len > 0) ? end - 1 : 0;
  float edv = layer ? ed3[node] : edinv2[node].x;
  float4 aL = {0,0,0,0}, aH = {0,0,0,0};
  float ss = 0.f;
  for (int off = 0; off < lenmax; off += 16){
    int sA[4]; float4 vr[4]; float p[4];
    #pragma unroll
    for (int u = 0; u < 4; ++u){
      int idx = beg + off + (u << 2) + slot2;
      sA[u] = srcs[idx < end ? idx : fallback];
    }
    #pragma unroll
    for (int u = 0; u < 4; ++u)
      vr[u] = *(const float4*)((const char*)h23 + ((unsigned)sA[u] << 7) + coff);
    #pragma unroll
    for (int u = 0; u < 4; ++u){
      float2 e2 = *(const float2*)((const char*)es23 + ((unsigned)sA[u] << 3));
      float esv = layer ? e2.y : e2.x;
      float e = __expf(leaky_relu(esv + edv));
      p[u] = ((off + (u << 2) + slot2) < len) ? e : 0.f;
    }
    #pragma unroll
    for (int u = 0; u < 4; ++u){
      ss += p[u];
      H8 hh; hh.f = vr[u];
      float2 c0 = __half22float2(hh.h[0]);
      float2 c1 = __half22float2(hh.h[1]);
      float2 c2 = __half22float2(hh.h[2]);
      float2 c3 = __half22float2(hh.h[3]);
      aL.x = fmaf(p[u], c0.x, aL.x); aL.y = fmaf(p[u], c0.y, aL.y);
      aL.z = fmaf(p[u], c1.x, aL.z); aL.w = fmaf(p[u], c1.y, aL.w);
      aH.x = fmaf(p[u], c2.x, aH.x); aH.y = fmaf(p[u], c2.y, aH.y);
      aH.z = fmaf(p[u], c3.x, aH.z); aH.w = fmaf(p[u], c3.y, aH.w);
    }
  }
  #pragma unroll
  for (int off = 8; off <= 16; off <<= 1){
    aL.x += __shfl_xor(aL.x, off, 64); aL.y += __shfl_xor(aL.y, off, 64);
    aL.z += __shfl_xor(aL.z, off, 64); aL.w += __shfl_xor(aL.w, off, 64);
    aH.x += __shfl_xor(aH.x, off, 64); aH.y += __shfl_xor(aH.y, off, 64);
    aH.z += __shfl_xor(aH.z, off, 64); aH.w += __shfl_xor(aH.w, off, 64);
    ss   += __shfl_xor(ss,   off, 64);
  }

  // layer-3 self loop (gated to layer lanes; per-half node scalars)
  {
    float psr = __expf(leaky_relu(es23[node].y + ed3[node]));
    float psg = layer ? psr : 0.f;
    H8 hh; hh.f = *(const float4*)((const char*)h23 + ((unsigned)node << 7) + coff);
    float2 c0 = __half22float2(hh.h[0]);
    float2 c1 = __half22float2(hh.h[1]);
    float2 c2 = __half22float2(hh.h[2]);
    float2 c3 = __half22float2(hh.h[3]);
    aL.x = fmaf(psg, c0.x, aL.x); aL.y = fmaf(psg, c0.y, aL.y);
    aL.z = fmaf(psg, c1.x, aL.z); aL.w = fmaf(psg, c1.y, aL.w);
    aH.x = fmaf(psg, c2.x, aH.x); aH.y = fmaf(psg, c2.y, aH.y);
    aH.z = fmaf(psg, c3.x, aH.z); aH.w = fmaf(psg, c3.y, aH.w);
    ss += psg;
  }
  float inv = 1.f / (ss + 1e-16f);

  float m0=0,m1=0,m2=0,m3=0,m4=0,m5=0,m6=0,m7=0;
  if (!layer){
    int ch0 = cg << 3;
    float4 bA = *(const float4*)&b2[ch0];
    float4 bB = *(const float4*)&b2[ch0 + 4];
    m0 = aL.x * inv + bA.x; m0 = m0 > 0.f ? m0 : 0.f;
    m1 = aL.y * inv + bA.y; m1 = m1 > 0.f ? m1 : 0.f;
    m2 = aL.z * inv + bA.z; m2 = m2 > 0.f ? m2 : 0.f;
    m3 = aL.w * inv + bA.w; m3 = m3 > 0.f ? m3 : 0.f;
    m4 = aH.x * inv + bB.x; m4 = m4 > 0.f ? m4 : 0.f;
    m5 = aH.y * inv + bB.y; m5 = m5 > 0.f ? m5 : 0.f;
    m6 = aH.z * inv + bB.z; m6 = m6 > 0.f ? m6 : 0.f;
    m7 = aH.w * inv + bB.w; m7 = m7 > 0.f ? m7 : 0.f;
  } else if (slot2 == 0){
    int ch0 = (cg & 3) << 3;
    float4 bA = *(const float4*)&b3[ch0];
    float4 bB = *(const float4*)&b3[ch0 + 4];
    float4 oA = { aL.x * inv + bA.x, aL.y * inv + bA.y, aL.z * inv + bA.z, aL.w * inv + bA.w };
    float4 oB = { aH.x * inv + bB.x, aH.y * inv + bB.y, aH.z * inv + bB.z, aH.w * inv + bB.w };
    *(float4*)&var_out[(size_t)node * D_OUTF + ch0]     = oA;
    *(float4*)&var_out[(size_t)node * D_OUTF + ch0 + 4] = oB;
  }

  // final linear on mean: out channel c = sub; m regs live on lanes (nh*32 + cgs), cgs 0-3
  {
    int c = sub;
    int lbase = lane & 32;
    float o = blin[c];
    #pragma unroll
    for (int cgs = 0; cgs < 4; ++cgs){
      int sl = lbase | cgs;
      float q0 = __shfl(m0, sl, 64), q1 = __shfl(m1, sl, 64);
      float q2 = __shfl(m2, sl, 64), q3 = __shfl(m3, sl, 64);
      float q4 = __shfl(m4, sl, 64), q5 = __shfl(m5, sl, 64);
      float q6 = __shfl(m6, sl, 64), q7 = __shfl(m7, sl, 64);
      int j0 = cgs << 3;
      o = fmaf(q0, sWl[(j0+0) * D_OUTF + c], o);
      o = fmaf(q1, sWl[(j0+1) * D_OUTF + c], o);
      o = fmaf(q2, sWl[(j0+2) * D_OUTF + c], o);
      o = fmaf(q3, sWl[(j0+3) * D_OUTF + c], o);
      o = fmaf(q4, sWl[(j0+4) * D_OUTF + c], o);
      o = fmaf(q5, sWl[(j0+5) * D_OUTF + c], o);
      o = fmaf(q6, sWl[(j0+6) * D_OUTF + c], o);
      o = fmaf(q7, sWl[(j0+7) * D_OUTF + c], o);
    }
    mean_out[(size_t)node * D_OUTF + c] = o;
  }
  if (sub == 0) edinv2[node].y = inv;   // cg==0 lane of each half is layer-2
}

// ------- alpha: flat edge-parallel, coalesced write, L2-hot gathers -------
__global__ __launch_bounds__(256) void k_alpha(const int* __restrict__ src,
    const int* __restrict__ dst,
    const float2* __restrict__ es23, const float2* __restrict__ edinv2,
    float* __restrict__ alpha_out){
  int e = blockIdx.x * blockDim.x + threadIdx.x;
  if (e < N_EDGES){
    int s = src[e], d = dst[e];
    float2 ei = *(const float2*)((const char*)edinv2 + ((unsigned)d << 3));
    float esv = ((const float2*)((const char*)es23 + ((unsigned)s << 3)))->x;
    alpha_out[e] = __expf(leaky_relu(esv + ei.x)) * ei.y;
  }
}

extern "C" void kernel_launch(void* const* d_in, const int* in_sizes, int n_in,
                              void* d_out, int out_size, void* d_ws, size_t ws_size,
                              hipStream_t stream) {
  const float* x   = (const float*)d_in[0];
  const int*   ei  = (const int*)d_in[1];
  const int*   src = ei;
  const int*   dst = ei + N_EDGES;
  const float* W1  = (const float*)d_in[2];
  const float* a1s = (const float*)d_in[3];
  const float* a1d = (const float*)d_in[4];
  const float* b1  = (const float*)d_in[5];
  const float* W2  = (const float*)d_in[6];
  const float* a2s = (const float*)d_in[7];
  const float* a2d = (const float*)d_in[8];
  const float* b2  = (const float*)d_in[9];
  const float* W3  = (const float*)d_in[10];
  const float* a3s = (const float*)d_in[11];
  const float* a3d = (const float*)d_in[12];
  const float* b3  = (const float*)d_in[13];
  const float* Wl  = (const float*)d_in[14];
  const float* bl  = (const float*)d_in[15];

  float* out       = (float*)d_out;
  float* mean_out  = out;
  float* var_out   = out + (size_t)N_NODES * D_OUTF;
  float* alpha_out = out + 2 * (size_t)N_NODES * D_OUTF;

  const int NSCAN = (N_NODES + 255) / 256;       // 196

  int* deg      = (int*)d_ws;                 // N
  int* rowptr   = deg + N_NODES;              // N+1
  int* bsum     = rowptr + (N_NODES + 1);     // NSCAN
  int* rank     = bsum + NSCAN;               // E
  int* srcs     = rank + N_EDGES;             // E
  size_t ioff   = (size_t)((srcs + N_EDGES) - (int*)d_ws);
  ioff = (ioff + 3) & ~(size_t)3;             // 16B align for half tables
  __half* h1    = (__half*)((int*)d_ws + ioff);     // N*64
  __half* h1act = h1 + (size_t)N_NODES * 64;        // N*64
  __half* h23   = h1act + (size_t)N_NODES * 64;     // N*64
  float* es1    = (float*)(h23 + (size_t)N_NODES * 64);
  float* ed1    = es1 + N_NODES;
  float* ed3    = ed1 + N_NODES;
  float* prew   = ed3 + N_NODES;              // 256 floats
  float2* es23  = (float2*)(prew + 256);
  float2* edinv2= es23 + N_NODES;

  k_zero  <<<NSCAN, 256, 0, stream>>>(deg);
  k_deg   <<<(N_EDGES + 255) / 256, 256, 0, stream>>>(dst, deg, rank);
  k_scan_a<<<NSCAN, 256, 0, stream>>>(deg, bsum);
  k_scan_b<<<1, 256, 0, stream>>>(bsum, NSCAN, W2, W3, a2s, a2d, a3s, a3d, prew);
  k_scan_c<<<NSCAN, 256, 0, stream>>>(deg, bsum, rowptr);
  k_fill  <<<(N_EDGES + 255) / 256, 256, 0, stream>>>(src, dst, rowptr, rank, srcs);

  k_gemm1<<<(N_NODES + 63) / 64, 256, 0, stream>>>(x, W1, a1s, a1d, h1, es1, ed1);
  k_agg1 <<<N_NODES / 8, 256, 0, stream>>>(rowptr, srcs, h1, es1, ed1, b1, h1act);
  k_gemm23<<<(N_NODES + 63) / 64, 256, 0, stream>>>(h1act, W2, W3, prew,
                                                    h23, es23, edinv2, ed3);
  k_agg23<<<N_NODES / 8, 256, 0, stream>>>(rowptr, srcs, h23, es23, edinv2, ed3,
                                           b2, b3, Wl, bl, mean_out, var_out);
  k_alpha<<<(N_EDGES + 255) / 256, 256, 0, stream>>>(src, dst, es23, edinv2, alpha_out);
}